// Round 14
// baseline (126.922 us; speedup 1.0000x reference)
//
#include <hip/hip_runtime.h>
#include <stdint.h>

#define B_ 2
#define S_ 2048
#define D_ 1024
#define H_ 16
#define HD_ 64
#define D3_ 3072
#define KD_ 1024

typedef __attribute__((ext_vector_type(8))) __bf16 bf16x8;
typedef __attribute__((ext_vector_type(4))) float f32x4;
typedef __attribute__((ext_vector_type(16))) float f32x16;
typedef __attribute__((ext_vector_type(4))) unsigned int u32x4;

typedef const __attribute__((address_space(1))) unsigned int gu32_t;
typedef __attribute__((address_space(3))) unsigned int lu32_t;

static __device__ __forceinline__ unsigned short f2bf(float f) {
  unsigned int u = __float_as_uint(f);
  u += 0x7fffu + ((u >> 16) & 1u);   // RNE (inputs finite)
  return (unsigned short)(u >> 16);
}

static __device__ __forceinline__ void gll16(const unsigned short* g, unsigned short* l) {
  __builtin_amdgcn_global_load_lds((gu32_t*)(const void*)g, (lu32_t*)(void*)l, 16, 0, 0);
}

static __device__ __forceinline__ bf16x8 lds_read8(const unsigned short* p) {
  return *reinterpret_cast<const bf16x8*>(p);
}

static __device__ __forceinline__ unsigned int cvtpk(float lo, float hi) {
  unsigned int r;
  asm("v_cvt_pk_bf16_f32 %0, %1, %2" : "=v"(r) : "v"(lo), "v"(hi));
  return r;
}

static __device__ __forceinline__ void plswap(unsigned int& a, unsigned int& b) {
  asm("v_permlane32_swap_b32 %0, %1" : "+v"(a), "+v"(b));
}

// ---------------- fused prep: cvt_bf16 | tcvt W_qkv | maskbits(+detect) | [tcvt W_dense] ----
// blocks [0,4096): hidden f32 -> bf16; [4096,7168): W_qkv transpose+cvt;
// [7168,8192): mask -> 1 bit/key with PER-BLOCK dtype detection (scans the same
// first 4096 words; all-zero regions give identical bits under any mode);
// [8192,9216): W_dense transpose (fused path only). Branch is block-uniform.
static __device__ __forceinline__ void transpose32(const float* __restrict__ in,
                                                   unsigned short* __restrict__ out,
                                                   int K, int N, int bx, int by, int t,
                                                   float (*tsm)[33]) {
  const int k0 = by * 32, n0 = bx * 32;
  const int tx = t & 31, ty = t >> 5;
  #pragma unroll
  for (int j = 0; j < 32; j += 8) tsm[ty + j][tx] = in[(size_t)(k0 + ty + j) * N + n0 + tx];
  __syncthreads();
  #pragma unroll
  for (int j = 0; j < 32; j += 8) out[(size_t)(n0 + ty + j) * K + k0 + tx] = f2bf(tsm[tx][ty + j]);
}

__global__ void prep_kernel(const float* __restrict__ hidden, unsigned short* __restrict__ Xb,
                            const float* __restrict__ Wq, unsigned short* __restrict__ Wqt,
                            const void* __restrict__ mask,
                            unsigned long long* __restrict__ bits,
                            const float* __restrict__ Wd, unsigned short* __restrict__ Wdt) {
  __shared__ float tsm[32][33];
  __shared__ unsigned int red2[2];
  const int bid = blockIdx.x;
  const int t = threadIdx.x;
  if (bid < 4096) {
    const int i = (bid * 256 + t) * 4;
    float4 v = *reinterpret_cast<const float4*>(hidden + i);
    unsigned long long p = (unsigned long long)f2bf(v.x)
                         | ((unsigned long long)f2bf(v.y) << 16)
                         | ((unsigned long long)f2bf(v.z) << 32)
                         | ((unsigned long long)f2bf(v.w) << 48);
    *reinterpret_cast<unsigned long long*>(Xb + i) = p;
  } else if (bid < 7168) {
    const int bb = bid - 4096;
    transpose32(Wq, Wqt, KD_, D3_, bb % 96, bb / 96, t, tsm);
  } else if (bid < 8192) {
    // local dtype detect (int32 vs int8 vs float) over first 4096 words
    if (t < 2) red2[t] = 0;
    __syncthreads();
    {
      const unsigned int* mw = (const unsigned int*)mask;
      unsigned int hb = 0, fl = 0;
      for (int i = t; i < 4096; i += 256) {
        unsigned int v = mw[i];
        hb |= (v & 0xFFFFFF00u);
        fl |= (v == 0x3F800000u) ? 1u : 0u;
      }
      atomicOr(&red2[0], hb);
      atomicOr(&red2[1], fl);
    }
    __syncthreads();
    const unsigned int mode = red2[1] ? 2u : (red2[0] ? 1u : 0u);
    const int lane = t & 63;
    const int nwaves = 1024 * 4;
    const int wid = ((bid - 7168) * 256 + t) >> 6;
    const int total = (B_ * S_ * S_) / 256;
    for (int wb = wid; wb < total; wb += nwaves) {
      const size_t base = (size_t)wb * 256 + lane;
      unsigned long long m0, m1, m2, m3;
      if (mode == 0) {
        const int* p = (const int*)mask;
        m0 = __ballot(p[base] != 0);       m1 = __ballot(p[base + 64] != 0);
        m2 = __ballot(p[base + 128] != 0); m3 = __ballot(p[base + 192] != 0);
      } else if (mode == 1) {
        const unsigned char* p = (const unsigned char*)mask;
        m0 = __ballot(p[base] != 0);       m1 = __ballot(p[base + 64] != 0);
        m2 = __ballot(p[base + 128] != 0); m3 = __ballot(p[base + 192] != 0);
      } else {
        const float* p = (const float*)mask;
        m0 = __ballot(p[base] != 0.f);       m1 = __ballot(p[base + 64] != 0.f);
        m2 = __ballot(p[base + 128] != 0.f); m3 = __ballot(p[base + 192] != 0.f);
      }
      if (lane < 4) {
        unsigned long long v = (lane & 1) ? m1 : m0;
        unsigned long long w2 = (lane & 1) ? m3 : m2;
        v = (lane & 2) ? w2 : v;
        bits[(size_t)wb * 4 + lane] = v;
      }
    }
  } else {
    const int bb = bid - 8192;                // 1024 blocks: W_dense 1024x1024
    transpose32(Wd, Wdt, D_, D_, bb & 31, bb >> 5, t, tsm);
  }
}

// ---------------- W_dense transpose fallback (ws too small for fused path) ----------------
__global__ void tcvt_kernel(const float* __restrict__ in, unsigned short* __restrict__ out, int K, int N) {
  __shared__ float tsm[32][33];
  transpose32(in, out, K, N, blockIdx.x, blockIdx.y, threadIdx.x, tsm);
}

// ---------------- QKV GEMM v4 (r11-proven): 256x192, dbuf BK=64, 1 barrier/K-tile ----------------
#define DSA256(BUF, MH, KC) \
  _Pragma("unroll") for (int fm_ = 0; fm_ < 4; ++fm_) \
    aq[fm_] = lds_read8(&Al[BUF][(wm * 128 + (MH) * 64 + fm_ * 16 + c16) * 64 + (KC)]);
#define DSB256(BUF, KC) \
  _Pragma("unroll") for (int fn_ = 0; fn_ < 3; ++fn_) \
    bq[fn_] = lds_read8(&Bl[BUF][(wn * 48 + fn_ * 16 + c16) * 64 + (KC)]);
#define MM256(MH) \
  __builtin_amdgcn_s_setprio(1); \
  _Pragma("unroll") for (int fm_ = 0; fm_ < 4; ++fm_) \
    _Pragma("unroll") for (int fn_ = 0; fn_ < 3; ++fn_) \
      acc[MH][fm_][fn_] = __builtin_amdgcn_mfma_f32_16x16x32_bf16(aq[fm_], bq[fn_], acc[MH][fm_][fn_], 0, 0, 0); \
  __builtin_amdgcn_s_setprio(0);
#define STA256(BUF, KT1) \
  _Pragma("unroll") for (int q_ = 0; q_ < 4; ++q_) \
    gll16(Ag + (size_t)(q_ * 64) * KD_ + (size_t)(KT1) * 64, &Al[BUF][q_ * 4096 + t * 8]);
#define STB256(BUF, KT1) \
  _Pragma("unroll") for (int q_ = 0; q_ < 3; ++q_) \
    gll16(Bg + (size_t)(q_ * 64) * KD_ + (size_t)(KT1) * 64, &Bl[BUF][q_ * 4096 + t * 8]);

__global__ __launch_bounds__(512, 2) void gemm256_kernel(
    const unsigned short* __restrict__ A,
    const unsigned short* __restrict__ Bt,
    const float* __restrict__ bias,
    unsigned short* __restrict__ Qh,
    unsigned short* __restrict__ Kh,
    unsigned short* __restrict__ Vt) {
  __shared__ unsigned short Al[2][16384];   // 256 rows x 64
  __shared__ unsigned short Bl[2][12288];   // 192 rows x 64
  const int t = threadIdx.x;
  const int lane = t & 63, w = t >> 6;
  const int g = lane >> 4, c16 = lane & 15;
  const int wm = w >> 2, wn = w & 3;

  // bijective XCD swizzle: 256 blocks = 8 XCDs x 32 (2 contiguous M-panels per XCD)
  const int wg = blockIdx.x;
  const int sw = (wg & 7) * 32 + (wg >> 3);
  const int by = sw >> 4, bx = sw & 15;     // 16 M-tiles x 16 N-tiles
  const int m0 = by * 256, n0 = bx * 192;

  f32x4 acc[2][4][3];
  #pragma unroll
  for (int mh = 0; mh < 2; ++mh)
    #pragma unroll
    for (int fm = 0; fm < 4; ++fm)
      #pragma unroll
      for (int fn = 0; fn < 3; ++fn)
        #pragma unroll
        for (int r = 0; r < 4; ++r) acc[mh][fm][fn][r] = 0.f;

  const int srow = t >> 3;
  const int scb = (t & 7) ^ (srow & 7);
  const unsigned short* Ag = A + (size_t)(m0 + srow) * KD_ + scb * 8;
  const unsigned short* Bg = Bt + (size_t)(n0 + srow) * KD_ + scb * 8;

  const int kc0 = ((g ^ (c16 & 7)) * 8);
  const int kc1 = (((4 + g) ^ (c16 & 7)) * 8);

  bf16x8 aq[4], bq[3];

  STA256(0, 0); STB256(0, 0);
  __syncthreads();

  #pragma unroll 1
  for (int kt = 0; kt < 16; ++kt) {
    const int buf = kt & 1, nb = buf ^ 1;
    const bool st = kt < 15;
    DSA256(buf, 0, kc0); DSB256(buf, kc0);
    if (st) STA256(nb, kt + 1);
    MM256(0);
    DSA256(buf, 1, kc0);
    if (st) STB256(nb, kt + 1);
    MM256(1);
    DSA256(buf, 0, kc1); DSB256(buf, kc1);
    MM256(0);
    DSA256(buf, 1, kc1);
    MM256(1);
    __syncthreads();
  }

  #pragma unroll
  for (int mh = 0; mh < 2; ++mh) {
    #pragma unroll
    for (int fn = 0; fn < 3; ++fn) {
      const int n = n0 + wn * 48 + fn * 16 + c16;
      const float bv = bias[n];
      const int sel = n >> 10;          // 0:q 1:k 2:v
      const int hh = (n & 1023) >> 6;
      const int d = n & 63;
      #pragma unroll
      for (int fm = 0; fm < 4; ++fm) {
        const int m_b = m0 + wm * 128 + mh * 64 + fm * 16 + g * 4;
        const int b = m_b >> 11;
        const int s0 = m_b & 2047;
        const int bh = b * H_ + hh;
        if (sel == 2) {
          ushort4 pk;
          pk.x = f2bf(acc[mh][fm][fn][0] + bv);
          pk.y = f2bf(acc[mh][fm][fn][1] + bv);
          pk.z = f2bf(acc[mh][fm][fn][2] + bv);
          pk.w = f2bf(acc[mh][fm][fn][3] + bv);
          *reinterpret_cast<ushort4*>(&Vt[(size_t)(bh * HD_ + d) * S_ + s0]) = pk;
        } else {
          #pragma unroll
          for (int r = 0; r < 4; ++r) {
            const float v = acc[mh][fm][fn][r] + bv;
            if (sel == 0) Qh[(size_t)(bh * S_ + s0 + r) * HD_ + d] = f2bf(v * 0.18033688011112042f);
            else          Kh[(size_t)(bh * S_ + s0 + r) * HD_ + d] = f2bf(v);
          }
        }
      }
    }
  }
}

// ---------------- dense GEMM v2 (unchanged from round 10) ----------------
#define DDA(BUF, KC) \
  _Pragma("unroll") for (int i_ = 0; i_ < 4; ++i_) \
    aq[i_] = lds_read8(&Al[BUF][(wr * 64 + i_ * 16 + c16) * 64 + (KC)]);
#define DDB(BUF, KC) \
  _Pragma("unroll") for (int i_ = 0; i_ < 4; ++i_) \
    bq[i_] = lds_read8(&Bl[BUF][(wc * 64 + i_ * 16 + c16) * 64 + (KC)]);
#define DMM \
  __builtin_amdgcn_s_setprio(1); \
  _Pragma("unroll") for (int mi_ = 0; mi_ < 4; ++mi_) \
    _Pragma("unroll") for (int ni_ = 0; ni_ < 4; ++ni_) \
      acc[mi_][ni_] = __builtin_amdgcn_mfma_f32_16x16x32_bf16(aq[mi_], bq[ni_], acc[mi_][ni_], 0, 0, 0); \
  __builtin_amdgcn_s_setprio(0);
#define DSTA(BUF, KT1) \
  _Pragma("unroll") for (int q_ = 0; q_ < 4; ++q_) \
    gll16(Ag + (size_t)(q_ * 32) * KD_ + (size_t)(KT1) * 64, &Al[BUF][q_ * 2048 + t * 8]);
#define DSTB(BUF, KT1) \
  _Pragma("unroll") for (int q_ = 0; q_ < 4; ++q_) \
    gll16(Bg + (size_t)(q_ * 32) * KD_ + (size_t)(KT1) * 64, &Bl[BUF][q_ * 2048 + t * 8]);

__global__ __launch_bounds__(256, 2) void gemm128p_kernel(
    const unsigned short* __restrict__ A,
    const unsigned short* __restrict__ Bt,
    const float* __restrict__ bias,
    int Ndim,
    float* __restrict__ Out) {
  __shared__ unsigned short Al[2][8192];
  __shared__ unsigned short Bl[2][8192];
  const int t = threadIdx.x;
  const int lane = t & 63, w = t >> 6;
  const int g = lane >> 4, c16 = lane & 15;
  const int wr = w >> 1, wc = w & 1;

  const int wg = blockIdx.x;
  const int sw = (wg & 7) * 32 + (wg >> 3);
  const int by = sw >> 3, bx = sw & 7;
  const int m0 = by * 128, n0 = bx * 128;

  f32x4 acc[4][4];
  #pragma unroll
  for (int mi = 0; mi < 4; ++mi)
    #pragma unroll
    for (int ni = 0; ni < 4; ++ni)
      #pragma unroll
      for (int r = 0; r < 4; ++r) acc[mi][ni][r] = 0.f;

  const int srow = t >> 3;
  const int scb = (t & 7) ^ (srow & 7);
  const unsigned short* Ag = A + (size_t)(m0 + srow) * KD_ + scb * 8;
  const unsigned short* Bg = Bt + (size_t)(n0 + srow) * KD_ + scb * 8;

  const int kc0 = ((g ^ (c16 & 7)) * 8);
  const int kc1 = (((4 + g) ^ (c16 & 7)) * 8);

  bf16x8 aq[4], bq[4];

  DSTA(0, 0); DSTB(0, 0);
  __syncthreads();

  #pragma unroll 1
  for (int kt = 0; kt < 16; ++kt) {
    const int buf = kt & 1, nb = buf ^ 1;
    const bool st = kt < 15;
    DDA(buf, kc0); DDB(buf, kc0);
    if (st) DSTA(nb, kt + 1);
    DMM;
    DDA(buf, kc1); DDB(buf, kc1);
    if (st) DSTB(nb, kt + 1);
    DMM;
    __syncthreads();
  }

  #pragma unroll
  for (int ni = 0; ni < 4; ++ni) {
    const int n = n0 + wc * 64 + ni * 16 + c16;
    const float bv = bias[n];
    #pragma unroll
    for (int mi = 0; mi < 4; ++mi) {
      #pragma unroll
      for (int r = 0; r < 4; ++r) {
        const int m = m0 + wr * 64 + mi * 16 + g * 4 + r;
        Out[(size_t)m * Ndim + n] = acc[mi][ni][r] + bv;
      }
    }
  }
}

// ---------------- flash attention v6 + XCD-aware block swizzle (unchanged) ----------------
#define PPOS(r) ((((r) & 3)) + 8 * ((r) >> 2))

#define SOFTPACK(SV, WQ, FLO, FHI) do {                                         \
    float p_[16];                                                               \
    _Pragma("unroll") for (int r_ = 0; r_ < 16; ++r_) {                         \
      float e_ = __builtin_amdgcn_exp2f((SV)[r_]);                              \
      int m_;                                                                   \
      asm("v_bfe_i32 %0, %1, %2, 1" : "=v"(m_) : "v"(WQ), "i"(PPOS(r_)));       \
      p_[r_] = __uint_as_float(__float_as_uint(e_) & (unsigned int)m_);         \
    }                                                                           \
    {                                                                           \
      unsigned int a0 = cvtpk(p_[0], p_[1]),  a1 = cvtpk(p_[2], p_[3]);         \
      unsigned int b0 = cvtpk(p_[4], p_[5]),  b1 = cvtpk(p_[6], p_[7]);         \
      plswap(a0, b0); plswap(a1, b1);                                           \
      u32x4 t_; t_[0] = a0; t_[1] = a1; t_[2] = b0; t_[3] = b1;                 \
      FLO = __builtin_bit_cast(bf16x8, t_);                                     \
    }                                                                           \
    {                                                                           \
      unsigned int a0 = cvtpk(p_[8], p_[9]),   a1 = cvtpk(p_[10], p_[11]);      \
      unsigned int b0 = cvtpk(p_[12], p_[13]), b1 = cvtpk(p_[14], p_[15]);      \
      plswap(a0, b0); plswap(a1, b1);                                           \
      u32x4 t_; t_[0] = a0; t_[1] = a1; t_[2] = b0; t_[3] = b1;                 \
      FHI = __builtin_bit_cast(bf16x8, t_);                                     \
    }                                                                           \
  } while (0)

#define PROC_KT(BUF, KT, WQW) do {                                              \
    f32x16 s0_;                                                                 \
    {                                                                           \
      bf16x8 kf_ = lds_read8(&sm[vp[0] + (BUF) * 8192 + (KT) * 2048]);          \
      s0_ = __builtin_amdgcn_mfma_f32_32x32x16_bf16(kf_, qf[0], zacc, 0, 0, 0); \
    }                                                                           \
    _Pragma("unroll") for (int kc_ = 1; kc_ < 4; ++kc_) {                       \
      bf16x8 kf_ = lds_read8(&sm[vp[kc_] + (BUF) * 8192 + (KT) * 2048]);        \
      s0_ = __builtin_amdgcn_mfma_f32_32x32x16_bf16(kf_, qf[kc_], s0_, 0, 0, 0); \
    }                                                                           \
    unsigned int wq_ = (WQW) >> sh4;                                            \
    bf16x8 paL_, paH_;                                                          \
    SOFTPACK(s0_, wq_, paL_, paH_);                                             \
    rsum = __builtin_amdgcn_mfma_f32_32x32x16_bf16(paL_, ones, rsum, 0, 0, 0);  \
    rsum = __builtin_amdgcn_mfma_f32_32x32x16_bf16(paH_, ones, rsum, 0, 0, 0);  \
    {                                                                           \
      bf16x8 vf0_ = lds_read8(&sm[vp[(KT)*2 + 0] + (BUF) * 8192 + 4096]);       \
      bf16x8 vf1_ = lds_read8(&sm[vp[(KT)*2 + 0] + (BUF) * 8192 + 4096 + 2048]); \
      ctx0 = __builtin_amdgcn_mfma_f32_32x32x16_bf16(paL_, vf0_, ctx0, 0, 0, 0); \
      ctx1 = __builtin_amdgcn_mfma_f32_32x32x16_bf16(paL_, vf1_, ctx1, 0, 0, 0); \
    }                                                                           \
    {                                                                           \
      bf16x8 vf0_ = lds_read8(&sm[vp[(KT)*2 + 1] + (BUF) * 8192 + 4096]);       \
      bf16x8 vf1_ = lds_read8(&sm[vp[(KT)*2 + 1] + (BUF) * 8192 + 4096 + 2048]); \
      ctx0 = __builtin_amdgcn_mfma_f32_32x32x16_bf16(paH_, vf0_, ctx0, 0, 0, 0); \
      ctx1 = __builtin_amdgcn_mfma_f32_32x32x16_bf16(paH_, vf1_, ctx1, 0, 0, 0); \
    }                                                                           \
  } while (0)

#define STAGE_TO(DBUF) do {                                                     \
    gll16(Kg,         &sm[kvb + (DBUF) * 8192 + qc1024]);                       \
    gll16(Kg + 512,   &sm[kvb + (DBUF) * 8192 + qc1024 + 512]);                 \
    gll16(Vg,         &sm[kvb + (DBUF) * 8192 + 4096 + qc1024]);                \
    gll16(Vg + 16384, &sm[kvb + (DBUF) * 8192 + 4096 + qc1024 + 512]);          \
    Kg += 4096; Vg += 64;                                                       \
  } while (0)

#define TILE64(BUF, KB, DOSTAGE) do {                                           \
    const uint2 mw_ = *(const uint2*)(mp + 2 * (KB));                           \
    if (DOSTAGE) STAGE_TO((BUF) ^ 1);                                           \
    PROC_KT(BUF, 0, mw_.x);                                                     \
    PROC_KT(BUF, 1, mw_.y);                                                     \
    __syncthreads();                                                            \
  } while (0)

__global__ __launch_bounds__(512, 4) void flash_kernel(
    const unsigned short* __restrict__ Qh,
    const unsigned short* __restrict__ Kh,
    const unsigned short* __restrict__ Vt,
    const unsigned long long* __restrict__ mbits,
    unsigned short* __restrict__ Ctx) {
  __shared__ unsigned short sm[32768];   // [grp][buf]{ K 64x64 | V 64x64 } bf16, xor-swizzled
  const int t = threadIdx.x;
  const int lane = t & 63, w = t >> 6;
  const int hi = lane >> 5, l31 = lane & 31;
  const int grp = w >> 2, qc = w & 3;

  // XCD-aware swizzle: all 16 q-tiles of one (b,h) -> same XCD (K/V L2 locality)
  const int lin = blockIdx.x;
  const int swz = (lin & 7) * 64 + (lin >> 3);
  const int qt = swz & 15, bhid = swz >> 4;
  const int h = bhid & 15, b = bhid >> 4;

  const int bh = b * H_ + h;
  const int qrow = qt * 128 + qc * 32 + l31;
  const int sh4 = hi * 4;
  const int kvb = grp * 16384;
  const int qc1024 = qc * 1024;

  bf16x8 qf[4];
  {
    const unsigned short* Qr = Qh + (size_t)(bh * S_ + qrow) * HD_ + hi * 8;
    #pragma unroll
    for (int kc = 0; kc < 4; ++kc) qf[kc] = *reinterpret_cast<const bf16x8*>(Qr + kc * 16);
  }

  f32x16 ctx0, ctx1, rsum, zacc;
  #pragma unroll
  for (int i = 0; i < 16; ++i) { ctx0[i] = 0.f; ctx1[i] = 0.f; rsum[i] = 0.f; zacc[i] = 0.f; }
  bf16x8 ones;
  #pragma unroll
  for (int i = 0; i < 8; ++i) ones[i] = (__bf16)1.0f;

  int vp[4];
  #pragma unroll
  for (int c = 0; c < 4; ++c)
    vp[c] = grp * 16384 + l31 * 64 + (((2 * c + hi) ^ (l31 & 7)) * 8);

  const unsigned int* mp =
      (const unsigned int*)(mbits + (size_t)(b * S_ + qrow) * 32) + grp * 32;

  const int srw = lane >> 3;
  const int scb = (lane & 7) ^ (srw & 7);
  const unsigned short* Kg = Kh + (size_t)(bh * S_ + grp * 1024 + qc * 16 + srw) * HD_ + scb * 8;
  const unsigned short* Vg = Vt + (size_t)(bh * HD_ + qc * 16 + srw) * S_ + grp * 1024 + scb * 8;

  STAGE_TO(0);
  __syncthreads();

  #pragma unroll 1
  for (int kb = 0; kb < 16; kb += 2) {
    TILE64(0, kb, 1);
    TILE64(1, kb + 1, (kb < 14));
  }

  // ---- combine across key-split groups (partner wave = w^4) via LDS ----
  float* creg = (float*)sm;
  if (grp == 1) {
    float* ex = creg + qc * 3072 + lane;
    #pragma unroll
    for (int r = 0; r < 16; ++r) {
      ex[r * 64] = ctx0[r];
      ex[(16 + r) * 64] = ctx1[r];
      ex[(32 + r) * 64] = rsum[r];
    }
  }
  __syncthreads();
  if (grp == 0) {
    const float* im = creg + qc * 3072 + lane;
    #pragma unroll
    for (int r = 0; r < 16; ++r) {
      const float c0 = ctx0[r] + im[r * 64];
      const float c1 = ctx1[r] + im[(16 + r) * 64];
      const float rt = rsum[r] + im[(32 + r) * 64];
      const float iv = 1.0f / rt;
      const int sq = qt * 128 + qc * 32 + PPOS(r) + 4 * hi;
      unsigned short* op = Ctx + (size_t)(b * S_ + sq) * D_ + h * HD_ + l31;
      op[0]  = f2bf(c0 * iv);
      op[32] = f2bf(c1 * iv);
    }
  }
}

extern "C" void kernel_launch(void* const* d_in, const int* in_sizes, int n_in,
                              void* d_out, int out_size, void* d_ws, size_t ws_size,
                              hipStream_t stream) {
  const float* hidden  = (const float*)d_in[0];
  const void*  mask    = d_in[1];
  const float* W_qkv   = (const float*)d_in[2];
  const float* b_qkv   = (const float*)d_in[3];
  const float* W_dense = (const float*)d_in[4];
  const float* b_dense = (const float*)d_in[5];
  float* out = (float*)d_out;

  char* ws = (char*)d_ws;
  unsigned short* Qh   = (unsigned short*)(ws);                 // 8 MB
  unsigned short* Kh   = (unsigned short*)(ws + 8388608);       // 8 MB
  unsigned short* Vtb  = (unsigned short*)(ws + 16777216);      // 8 MB
  unsigned short* Xb   = (unsigned short*)(ws + 25165824);      // 8 MB (reused as Ctx)
  unsigned short* Ctx  = Xb;                                    // Xb dead after QKV GEMM
  unsigned short* Wqt  = (unsigned short*)(ws + 33554432);      // 6 MB (reused for Wdt in fallback)
  unsigned long long* mbits = (unsigned long long*)(ws + 39845888); // 1 MB

  const bool fused = ws_size >= 44040192ull;
  unsigned short* Wdt = fused ? (unsigned short*)(ws + 41943040) : Wqt;

  prep_kernel<<<fused ? 9216 : 8192, 256, 0, stream>>>(
      hidden, Xb, W_qkv, Wqt, mask, mbits, W_dense, Wdt);

  gemm256_kernel<<<256, 512, 0, stream>>>(Xb, Wqt, b_qkv, Qh, Kh, Vtb);

  if (!fused)
    tcvt_kernel<<<dim3(D_ / 32, D_ / 32), 256, 0, stream>>>(W_dense, Wdt, D_, D_);

  flash_kernel<<<512, 512, 0, stream>>>(Qh, Kh, Vtb, mbits, Ctx);

  gemm128p_kernel<<<256, 256, 0, stream>>>(Ctx, Wdt, b_dense, D_, out);
}

// Round 16
// 125.738 us; speedup vs baseline: 1.0094x; 1.0094x over previous
//
#include <hip/hip_runtime.h>
#include <stdint.h>

#define B_ 2
#define S_ 2048
#define D_ 1024
#define H_ 16
#define HD_ 64
#define D3_ 3072
#define KD_ 1024

typedef __attribute__((ext_vector_type(8))) __bf16 bf16x8;
typedef __attribute__((ext_vector_type(4))) float f32x4;
typedef __attribute__((ext_vector_type(16))) float f32x16;
typedef __attribute__((ext_vector_type(4))) unsigned int u32x4;

typedef const __attribute__((address_space(1))) unsigned int gu32_t;
typedef __attribute__((address_space(3))) unsigned int lu32_t;

static __device__ __forceinline__ unsigned short f2bf(float f) {
  unsigned int u = __float_as_uint(f);
  u += 0x7fffu + ((u >> 16) & 1u);   // RNE (inputs finite)
  return (unsigned short)(u >> 16);
}

static __device__ __forceinline__ void gll16(const unsigned short* g, unsigned short* l) {
  __builtin_amdgcn_global_load_lds((gu32_t*)(const void*)g, (lu32_t*)(void*)l, 16, 0, 0);
}

static __device__ __forceinline__ bf16x8 lds_read8(const unsigned short* p) {
  return *reinterpret_cast<const bf16x8*>(p);
}

static __device__ __forceinline__ unsigned int cvtpk(float lo, float hi) {
  unsigned int r;
  asm("v_cvt_pk_bf16_f32 %0, %1, %2" : "=v"(r) : "v"(lo), "v"(hi));
  return r;
}

static __device__ __forceinline__ void plswap(unsigned int& a, unsigned int& b) {
  asm("v_permlane32_swap_b32 %0, %1" : "+v"(a), "+v"(b));
}

// ---------------- fused prep: tcvt W_qkv | maskbits(+detect) | [tcvt W_dense] ----------------
// blocks [0,3072): W_qkv transpose+cvt; [3072,4096): mask -> 1 bit/key with per-block
// dtype detection; [4096,5120): W_dense transpose (fused path). Branch is block-uniform.
// (hidden f32->bf16 conversion is folded into gemm256's A reg-staging.)
static __device__ __forceinline__ void transpose32(const float* __restrict__ in,
                                                   unsigned short* __restrict__ out,
                                                   int K, int N, int bx, int by, int t,
                                                   float (*tsm)[33]) {
  const int k0 = by * 32, n0 = bx * 32;
  const int tx = t & 31, ty = t >> 5;
  #pragma unroll
  for (int j = 0; j < 32; j += 8) tsm[ty + j][tx] = in[(size_t)(k0 + ty + j) * N + n0 + tx];
  __syncthreads();
  #pragma unroll
  for (int j = 0; j < 32; j += 8) out[(size_t)(n0 + ty + j) * K + k0 + tx] = f2bf(tsm[tx][ty + j]);
}

__global__ void prep_kernel(const float* __restrict__ Wq, unsigned short* __restrict__ Wqt,
                            const void* __restrict__ mask,
                            unsigned long long* __restrict__ bits,
                            const float* __restrict__ Wd, unsigned short* __restrict__ Wdt) {
  __shared__ float tsm[32][33];
  __shared__ unsigned int red2[2];
  const int bid = blockIdx.x;
  const int t = threadIdx.x;
  if (bid < 3072) {
    transpose32(Wq, Wqt, KD_, D3_, bid % 96, bid / 96, t, tsm);
  } else if (bid < 4096) {
    // local dtype detect (int32 vs int8 vs float) over first 4096 words
    if (t < 2) red2[t] = 0;
    __syncthreads();
    {
      const unsigned int* mw = (const unsigned int*)mask;
      unsigned int hb = 0, fl = 0;
      for (int i = t; i < 4096; i += 256) {
        unsigned int v = mw[i];
        hb |= (v & 0xFFFFFF00u);
        fl |= (v == 0x3F800000u) ? 1u : 0u;
      }
      atomicOr(&red2[0], hb);
      atomicOr(&red2[1], fl);
    }
    __syncthreads();
    const unsigned int mode = red2[1] ? 2u : (red2[0] ? 1u : 0u);
    const int lane = t & 63;
    const int nwaves = 1024 * 4;
    const int wid = ((bid - 3072) * 256 + t) >> 6;
    const int total = (B_ * S_ * S_) / 256;
    for (int wb = wid; wb < total; wb += nwaves) {
      const size_t base = (size_t)wb * 256 + lane;
      unsigned long long m0, m1, m2, m3;
      if (mode == 0) {
        const int* p = (const int*)mask;
        m0 = __ballot(p[base] != 0);       m1 = __ballot(p[base + 64] != 0);
        m2 = __ballot(p[base + 128] != 0); m3 = __ballot(p[base + 192] != 0);
      } else if (mode == 1) {
        const unsigned char* p = (const unsigned char*)mask;
        m0 = __ballot(p[base] != 0);       m1 = __ballot(p[base + 64] != 0);
        m2 = __ballot(p[base + 128] != 0); m3 = __ballot(p[base + 192] != 0);
      } else {
        const float* p = (const float*)mask;
        m0 = __ballot(p[base] != 0.f);       m1 = __ballot(p[base + 64] != 0.f);
        m2 = __ballot(p[base + 128] != 0.f); m3 = __ballot(p[base + 192] != 0.f);
      }
      if (lane < 4) {
        unsigned long long v = (lane & 1) ? m1 : m0;
        unsigned long long w2 = (lane & 1) ? m3 : m2;
        v = (lane & 2) ? w2 : v;
        bits[(size_t)wb * 4 + lane] = v;
      }
    }
  } else {
    const int bb = bid - 4096;                // 1024 blocks: W_dense 1024x1024
    transpose32(Wd, Wdt, D_, D_, bb & 31, bb >> 5, t, tsm);
  }
}

// ---------------- W_dense transpose fallback (ws too small for fused path) ----------------
__global__ void tcvt_kernel(const float* __restrict__ in, unsigned short* __restrict__ out, int K, int N) {
  __shared__ float tsm[32][33];
  transpose32(in, out, K, N, blockIdx.x, blockIdx.y, threadIdx.x, tsm);
}

// ---------------- QKV GEMM v6: 256x192, dbuf BK=64, 1 barrier/K-tile ----------------
// A comes directly from hidden f32 via reg-staging (issue-early loads, cvt_pk +
// ds_write-late) -- deletes the separate cvt pre-pass. B stays on global_load_lds.
// LDS layout and read pattern identical to the proven r11 kernel.
#define DSA256(BUF, MH, KC) \
  _Pragma("unroll") for (int fm_ = 0; fm_ < 4; ++fm_) \
    aq[fm_] = lds_read8(&Al[BUF][(wm * 128 + (MH) * 64 + fm_ * 16 + c16) * 64 + (KC)]);
#define DSB256(BUF, KC) \
  _Pragma("unroll") for (int fn_ = 0; fn_ < 3; ++fn_) \
    bq[fn_] = lds_read8(&Bl[BUF][(wn * 48 + fn_ * 16 + c16) * 64 + (KC)]);
#define MM256(MH) \
  __builtin_amdgcn_s_setprio(1); \
  _Pragma("unroll") for (int fm_ = 0; fm_ < 4; ++fm_) \
    _Pragma("unroll") for (int fn_ = 0; fn_ < 3; ++fn_) \
      acc[MH][fm_][fn_] = __builtin_amdgcn_mfma_f32_16x16x32_bf16(aq[fm_], bq[fn_], acc[MH][fm_][fn_], 0, 0, 0); \
  __builtin_amdgcn_s_setprio(0);
#define ALOAD256(KT1) \
  _Pragma("unroll") for (int q_ = 0; q_ < 4; ++q_) { \
    const float* s_ = Ag + (size_t)(q_ * 64) * KD_ + (size_t)(KT1) * 64; \
    fA[q_][0] = *reinterpret_cast<const float4*>(s_); \
    fA[q_][1] = *reinterpret_cast<const float4*>(s_ + 4); \
  }
#define AWRT256(BUF) \
  _Pragma("unroll") for (int q_ = 0; q_ < 4; ++q_) { \
    u32x4 pk_; \
    pk_[0] = cvtpk(fA[q_][0].x, fA[q_][0].y); \
    pk_[1] = cvtpk(fA[q_][0].z, fA[q_][0].w); \
    pk_[2] = cvtpk(fA[q_][1].x, fA[q_][1].y); \
    pk_[3] = cvtpk(fA[q_][1].z, fA[q_][1].w); \
    *reinterpret_cast<u32x4*>(&Al[BUF][q_ * 4096 + t * 8]) = pk_; \
  }
#define STB256(BUF, KT1) \
  _Pragma("unroll") for (int q_ = 0; q_ < 3; ++q_) \
    gll16(Bg + (size_t)(q_ * 64) * KD_ + (size_t)(KT1) * 64, &Bl[BUF][q_ * 4096 + t * 8]);

__global__ __launch_bounds__(512, 2) void gemm256_kernel(
    const float* __restrict__ Af,           // hidden f32 [4096][1024]
    const unsigned short* __restrict__ Bt,  // Wqt bf16 [3072][1024]
    const float* __restrict__ bias,
    unsigned short* __restrict__ Qh,
    unsigned short* __restrict__ Kh,
    unsigned short* __restrict__ Vt) {
  __shared__ unsigned short Al[2][16384];   // 256 rows x 64
  __shared__ unsigned short Bl[2][12288];   // 192 rows x 64
  const int t = threadIdx.x;
  const int lane = t & 63, w = t >> 6;
  const int g = lane >> 4, c16 = lane & 15;
  const int wm = w >> 2, wn = w & 3;

  // bijective XCD swizzle: 256 blocks = 8 XCDs x 32 (2 contiguous M-panels per XCD)
  const int wg = blockIdx.x;
  const int sw = (wg & 7) * 32 + (wg >> 3);
  const int by = sw >> 4, bx = sw & 15;     // 16 M-tiles x 16 N-tiles
  const int m0 = by * 256, n0 = bx * 192;

  f32x4 acc[2][4][3];
  #pragma unroll
  for (int mh = 0; mh < 2; ++mh)
    #pragma unroll
    for (int fm = 0; fm < 4; ++fm)
      #pragma unroll
      for (int fn = 0; fn < 3; ++fn)
        #pragma unroll
        for (int r = 0; r < 4; ++r) acc[mh][fm][fn][r] = 0.f;

  const int srow = t >> 3;
  const int scb = (t & 7) ^ (srow & 7);     // pre-swizzled source col-block
  const float* Ag = Af + (size_t)(m0 + srow) * KD_ + scb * 8;
  const unsigned short* Bg = Bt + (size_t)(n0 + srow) * KD_ + scb * 8;

  const int kc0 = ((g ^ (c16 & 7)) * 8);
  const int kc1 = (((4 + g) ^ (c16 & 7)) * 8);

  bf16x8 aq[4], bq[3];
  float4 fA[4][2];

  // prologue: tile 0
  ALOAD256(0);
  STB256(0, 0);
  AWRT256(0);
  __syncthreads();

  #pragma unroll 1
  for (int kt = 0; kt < 16; ++kt) {
    const int buf = kt & 1, nb = buf ^ 1;
    const bool st = kt < 15;
    if (st) ALOAD256(kt + 1);               // issue f32 loads early (full-tile cover)
    DSA256(buf, 0, kc0); DSB256(buf, kc0);
    MM256(0);
    DSA256(buf, 1, kc0);
    if (st) STB256(nb, kt + 1);
    MM256(1);
    DSA256(buf, 0, kc1); DSB256(buf, kc1);
    MM256(0);
    DSA256(buf, 1, kc1);
    if (st) AWRT256(nb);                    // cvt + ds_write late (after all reads of buf)
    MM256(1);
    __syncthreads();
  }

  #pragma unroll
  for (int mh = 0; mh < 2; ++mh) {
    #pragma unroll
    for (int fn = 0; fn < 3; ++fn) {
      const int n = n0 + wn * 48 + fn * 16 + c16;
      const float bv = bias[n];
      const int sel = n >> 10;          // 0:q 1:k 2:v
      const int hh = (n & 1023) >> 6;
      const int d = n & 63;
      #pragma unroll
      for (int fm = 0; fm < 4; ++fm) {
        const int m_b = m0 + wm * 128 + mh * 64 + fm * 16 + g * 4;
        const int b = m_b >> 11;
        const int s0 = m_b & 2047;
        const int bh = b * H_ + hh;
        if (sel == 2) {
          ushort4 pk;
          pk.x = f2bf(acc[mh][fm][fn][0] + bv);
          pk.y = f2bf(acc[mh][fm][fn][1] + bv);
          pk.z = f2bf(acc[mh][fm][fn][2] + bv);
          pk.w = f2bf(acc[mh][fm][fn][3] + bv);
          *reinterpret_cast<ushort4*>(&Vt[(size_t)(bh * HD_ + d) * S_ + s0]) = pk;
        } else {
          #pragma unroll
          for (int r = 0; r < 4; ++r) {
            const float v = acc[mh][fm][fn][r] + bv;
            if (sel == 0) Qh[(size_t)(bh * S_ + s0 + r) * HD_ + d] = f2bf(v * 0.18033688011112042f);
            else          Kh[(size_t)(bh * S_ + s0 + r) * HD_ + d] = f2bf(v);
          }
        }
      }
    }
  }
}

// ---------------- dense GEMM v2 (unchanged from round 10) ----------------
#define DDA(BUF, KC) \
  _Pragma("unroll") for (int i_ = 0; i_ < 4; ++i_) \
    aq[i_] = lds_read8(&Al[BUF][(wr * 64 + i_ * 16 + c16) * 64 + (KC)]);
#define DDB(BUF, KC) \
  _Pragma("unroll") for (int i_ = 0; i_ < 4; ++i_) \
    bq[i_] = lds_read8(&Bl[BUF][(wc * 64 + i_ * 16 + c16) * 64 + (KC)]);
#define DMM \
  __builtin_amdgcn_s_setprio(1); \
  _Pragma("unroll") for (int mi_ = 0; mi_ < 4; ++mi_) \
    _Pragma("unroll") for (int ni_ = 0; ni_ < 4; ++ni_) \
      acc[mi_][ni_] = __builtin_amdgcn_mfma_f32_16x16x32_bf16(aq[mi_], bq[ni_], acc[mi_][ni_], 0, 0, 0); \
  __builtin_amdgcn_s_setprio(0);
#define DSTA(BUF, KT1) \
  _Pragma("unroll") for (int q_ = 0; q_ < 4; ++q_) \
    gll16(Ag + (size_t)(q_ * 32) * KD_ + (size_t)(KT1) * 64, &Al[BUF][q_ * 2048 + t * 8]);
#define DSTB(BUF, KT1) \
  _Pragma("unroll") for (int q_ = 0; q_ < 4; ++q_) \
    gll16(Bg + (size_t)(q_ * 32) * KD_ + (size_t)(KT1) * 64, &Bl[BUF][q_ * 2048 + t * 8]);

__global__ __launch_bounds__(256, 2) void gemm128p_kernel(
    const unsigned short* __restrict__ A,
    const unsigned short* __restrict__ Bt,
    const float* __restrict__ bias,
    int Ndim,
    float* __restrict__ Out) {
  __shared__ unsigned short Al[2][8192];
  __shared__ unsigned short Bl[2][8192];
  const int t = threadIdx.x;
  const int lane = t & 63, w = t >> 6;
  const int g = lane >> 4, c16 = lane & 15;
  const int wr = w >> 1, wc = w & 1;

  const int wg = blockIdx.x;
  const int sw = (wg & 7) * 32 + (wg >> 3);
  const int by = sw >> 3, bx = sw & 7;
  const int m0 = by * 128, n0 = bx * 128;

  f32x4 acc[4][4];
  #pragma unroll
  for (int mi = 0; mi < 4; ++mi)
    #pragma unroll
    for (int ni = 0; ni < 4; ++ni)
      #pragma unroll
      for (int r = 0; r < 4; ++r) acc[mi][ni][r] = 0.f;

  const int srow = t >> 3;
  const int scb = (t & 7) ^ (srow & 7);
  const unsigned short* Ag = A + (size_t)(m0 + srow) * KD_ + scb * 8;
  const unsigned short* Bg = Bt + (size_t)(n0 + srow) * KD_ + scb * 8;

  const int kc0 = ((g ^ (c16 & 7)) * 8);
  const int kc1 = (((4 + g) ^ (c16 & 7)) * 8);

  bf16x8 aq[4], bq[4];

  DSTA(0, 0); DSTB(0, 0);
  __syncthreads();

  #pragma unroll 1
  for (int kt = 0; kt < 16; ++kt) {
    const int buf = kt & 1, nb = buf ^ 1;
    const bool st = kt < 15;
    DDA(buf, kc0); DDB(buf, kc0);
    if (st) DSTA(nb, kt + 1);
    DMM;
    DDA(buf, kc1); DDB(buf, kc1);
    if (st) DSTB(nb, kt + 1);
    DMM;
    __syncthreads();
  }

  #pragma unroll
  for (int ni = 0; ni < 4; ++ni) {
    const int n = n0 + wc * 64 + ni * 16 + c16;
    const float bv = bias[n];
    #pragma unroll
    for (int mi = 0; mi < 4; ++mi) {
      #pragma unroll
      for (int r = 0; r < 4; ++r) {
        const int m = m0 + wr * 64 + mi * 16 + g * 4 + r;
        Out[(size_t)m * Ndim + n] = acc[mi][ni][r] + bv;
      }
    }
  }
}

// ---------------- flash attention v6 + XCD-aware block swizzle (unchanged) ----------------
#define PPOS(r) ((((r) & 3)) + 8 * ((r) >> 2))

#define SOFTPACK(SV, WQ, FLO, FHI) do {                                         \
    float p_[16];                                                               \
    _Pragma("unroll") for (int r_ = 0; r_ < 16; ++r_) {                         \
      float e_ = __builtin_amdgcn_exp2f((SV)[r_]);                              \
      int m_;                                                                   \
      asm("v_bfe_i32 %0, %1, %2, 1" : "=v"(m_) : "v"(WQ), "i"(PPOS(r_)));       \
      p_[r_] = __uint_as_float(__float_as_uint(e_) & (unsigned int)m_);         \
    }                                                                           \
    {                                                                           \
      unsigned int a0 = cvtpk(p_[0], p_[1]),  a1 = cvtpk(p_[2], p_[3]);         \
      unsigned int b0 = cvtpk(p_[4], p_[5]),  b1 = cvtpk(p_[6], p_[7]);         \
      plswap(a0, b0); plswap(a1, b1);                                           \
      u32x4 t_; t_[0] = a0; t_[1] = a1; t_[2] = b0; t_[3] = b1;                 \
      FLO = __builtin_bit_cast(bf16x8, t_);                                     \
    }                                                                           \
    {                                                                           \
      unsigned int a0 = cvtpk(p_[8], p_[9]),   a1 = cvtpk(p_[10], p_[11]);      \
      unsigned int b0 = cvtpk(p_[12], p_[13]), b1 = cvtpk(p_[14], p_[15]);      \
      plswap(a0, b0); plswap(a1, b1);                                           \
      u32x4 t_; t_[0] = a0; t_[1] = a1; t_[2] = b0; t_[3] = b1;                 \
      FHI = __builtin_bit_cast(bf16x8, t_);                                     \
    }                                                                           \
  } while (0)

#define PROC_KT(BUF, KT, WQW) do {                                              \
    f32x16 s0_;                                                                 \
    {                                                                           \
      bf16x8 kf_ = lds_read8(&sm[vp[0] + (BUF) * 8192 + (KT) * 2048]);          \
      s0_ = __builtin_amdgcn_mfma_f32_32x32x16_bf16(kf_, qf[0], zacc, 0, 0, 0); \
    }                                                                           \
    _Pragma("unroll") for (int kc_ = 1; kc_ < 4; ++kc_) {                       \
      bf16x8 kf_ = lds_read8(&sm[vp[kc_] + (BUF) * 8192 + (KT) * 2048]);        \
      s0_ = __builtin_amdgcn_mfma_f32_32x32x16_bf16(kf_, qf[kc_], s0_, 0, 0, 0); \
    }                                                                           \
    unsigned int wq_ = (WQW) >> sh4;                                            \
    bf16x8 paL_, paH_;                                                          \
    SOFTPACK(s0_, wq_, paL_, paH_);                                             \
    rsum = __builtin_amdgcn_mfma_f32_32x32x16_bf16(paL_, ones, rsum, 0, 0, 0);  \
    rsum = __builtin_amdgcn_mfma_f32_32x32x16_bf16(paH_, ones, rsum, 0, 0, 0);  \
    {                                                                           \
      bf16x8 vf0_ = lds_read8(&sm[vp[(KT)*2 + 0] + (BUF) * 8192 + 4096]);       \
      bf16x8 vf1_ = lds_read8(&sm[vp[(KT)*2 + 0] + (BUF) * 8192 + 4096 + 2048]); \
      ctx0 = __builtin_amdgcn_mfma_f32_32x32x16_bf16(paL_, vf0_, ctx0, 0, 0, 0); \
      ctx1 = __builtin_amdgcn_mfma_f32_32x32x16_bf16(paL_, vf1_, ctx1, 0, 0, 0); \
    }                                                                           \
    {                                                                           \
      bf16x8 vf0_ = lds_read8(&sm[vp[(KT)*2 + 1] + (BUF) * 8192 + 4096]);       \
      bf16x8 vf1_ = lds_read8(&sm[vp[(KT)*2 + 1] + (BUF) * 8192 + 4096 + 2048]); \
      ctx0 = __builtin_amdgcn_mfma_f32_32x32x16_bf16(paH_, vf0_, ctx0, 0, 0, 0); \
      ctx1 = __builtin_amdgcn_mfma_f32_32x32x16_bf16(paH_, vf1_, ctx1, 0, 0, 0); \
    }                                                                           \
  } while (0)

#define STAGE_TO(DBUF) do {                                                     \
    gll16(Kg,         &sm[kvb + (DBUF) * 8192 + qc1024]);                       \
    gll16(Kg + 512,   &sm[kvb + (DBUF) * 8192 + qc1024 + 512]);                 \
    gll16(Vg,         &sm[kvb + (DBUF) * 8192 + 4096 + qc1024]);                \
    gll16(Vg + 16384, &sm[kvb + (DBUF) * 8192 + 4096 + qc1024 + 512]);          \
    Kg += 4096; Vg += 64;                                                       \
  } while (0)

#define TILE64(BUF, KB, DOSTAGE) do {                                           \
    const uint2 mw_ = *(const uint2*)(mp + 2 * (KB));                           \
    if (DOSTAGE) STAGE_TO((BUF) ^ 1);                                           \
    PROC_KT(BUF, 0, mw_.x);                                                     \
    PROC_KT(BUF, 1, mw_.y);                                                     \
    __syncthreads();                                                            \
  } while (0)

__global__ __launch_bounds__(512, 4) void flash_kernel(
    const unsigned short* __restrict__ Qh,
    const unsigned short* __restrict__ Kh,
    const unsigned short* __restrict__ Vt,
    const unsigned long long* __restrict__ mbits,
    unsigned short* __restrict__ Ctx) {
  __shared__ unsigned short sm[32768];   // [grp][buf]{ K 64x64 | V 64x64 } bf16, xor-swizzled
  const int t = threadIdx.x;
  const int lane = t & 63, w = t >> 6;
  const int hi = lane >> 5, l31 = lane & 31;
  const int grp = w >> 2, qc = w & 3;

  // XCD-aware swizzle: all 16 q-tiles of one (b,h) -> same XCD (K/V L2 locality)
  const int lin = blockIdx.x;
  const int swz = (lin & 7) * 64 + (lin >> 3);
  const int qt = swz & 15, bhid = swz >> 4;
  const int h = bhid & 15, b = bhid >> 4;

  const int bh = b * H_ + h;
  const int qrow = qt * 128 + qc * 32 + l31;
  const int sh4 = hi * 4;
  const int kvb = grp * 16384;
  const int qc1024 = qc * 1024;

  bf16x8 qf[4];
  {
    const unsigned short* Qr = Qh + (size_t)(bh * S_ + qrow) * HD_ + hi * 8;
    #pragma unroll
    for (int kc = 0; kc < 4; ++kc) qf[kc] = *reinterpret_cast<const bf16x8*>(Qr + kc * 16);
  }

  f32x16 ctx0, ctx1, rsum, zacc;
  #pragma unroll
  for (int i = 0; i < 16; ++i) { ctx0[i] = 0.f; ctx1[i] = 0.f; rsum[i] = 0.f; zacc[i] = 0.f; }
  bf16x8 ones;
  #pragma unroll
  for (int i = 0; i < 8; ++i) ones[i] = (__bf16)1.0f;

  int vp[4];
  #pragma unroll
  for (int c = 0; c < 4; ++c)
    vp[c] = grp * 16384 + l31 * 64 + (((2 * c + hi) ^ (l31 & 7)) * 8);

  const unsigned int* mp =
      (const unsigned int*)(mbits + (size_t)(b * S_ + qrow) * 32) + grp * 32;

  const int srw = lane >> 3;
  const int scb = (lane & 7) ^ (srw & 7);
  const unsigned short* Kg = Kh + (size_t)(bh * S_ + grp * 1024 + qc * 16 + srw) * HD_ + scb * 8;
  const unsigned short* Vg = Vt + (size_t)(bh * HD_ + qc * 16 + srw) * S_ + grp * 1024 + scb * 8;

  STAGE_TO(0);
  __syncthreads();

  #pragma unroll 1
  for (int kb = 0; kb < 16; kb += 2) {
    TILE64(0, kb, 1);
    TILE64(1, kb + 1, (kb < 14));
  }

  // ---- combine across key-split groups (partner wave = w^4) via LDS ----
  float* creg = (float*)sm;
  if (grp == 1) {
    float* ex = creg + qc * 3072 + lane;
    #pragma unroll
    for (int r = 0; r < 16; ++r) {
      ex[r * 64] = ctx0[r];
      ex[(16 + r) * 64] = ctx1[r];
      ex[(32 + r) * 64] = rsum[r];
    }
  }
  __syncthreads();
  if (grp == 0) {
    const float* im = creg + qc * 3072 + lane;
    #pragma unroll
    for (int r = 0; r < 16; ++r) {
      const float c0 = ctx0[r] + im[r * 64];
      const float c1 = ctx1[r] + im[(16 + r) * 64];
      const float rt = rsum[r] + im[(32 + r) * 64];
      const float iv = 1.0f / rt;
      const int sq = qt * 128 + qc * 32 + PPOS(r) + 4 * hi;
      unsigned short* op = Ctx + (size_t)(b * S_ + sq) * D_ + h * HD_ + l31;
      op[0]  = f2bf(c0 * iv);
      op[32] = f2bf(c1 * iv);
    }
  }
}

extern "C" void kernel_launch(void* const* d_in, const int* in_sizes, int n_in,
                              void* d_out, int out_size, void* d_ws, size_t ws_size,
                              hipStream_t stream) {
  const float* hidden  = (const float*)d_in[0];
  const void*  mask    = d_in[1];
  const float* W_qkv   = (const float*)d_in[2];
  const float* b_qkv   = (const float*)d_in[3];
  const float* W_dense = (const float*)d_in[4];
  const float* b_dense = (const float*)d_in[5];
  float* out = (float*)d_out;

  char* ws = (char*)d_ws;
  unsigned short* Qh   = (unsigned short*)(ws);                 // 8 MB
  unsigned short* Kh   = (unsigned short*)(ws + 8388608);       // 8 MB
  unsigned short* Vtb  = (unsigned short*)(ws + 16777216);      // 8 MB
  unsigned short* Ctx  = (unsigned short*)(ws + 25165824);      // 8 MB (flash out)
  unsigned short* Wqt  = (unsigned short*)(ws + 33554432);      // 6 MB (reused for Wdt in fallback)
  unsigned long long* mbits = (unsigned long long*)(ws + 39845888); // 1 MB

  const bool fused = ws_size >= 44040192ull;
  unsigned short* Wdt = fused ? (unsigned short*)(ws + 41943040) : Wqt;

  prep_kernel<<<fused ? 5120 : 4096, 256, 0, stream>>>(
      W_qkv, Wqt, mask, mbits, W_dense, Wdt);

  gemm256_kernel<<<256, 512, 0, stream>>>(hidden, Wqt, b_qkv, Qh, Kh, Vtb);

  if (!fused)
    tcvt_kernel<<<dim3(D_ / 32, D_ / 32), 256, 0, stream>>>(W_dense, Wdt, D_, D_);

  flash_kernel<<<512, 512, 0, stream>>>(Qh, Kh, Vtb, mbits, Ctx);

  gemm128p_kernel<<<256, 256, 0, stream>>>(Ctx, Wdt, b_dense, D_, out);
}

// Round 17
// 125.735 us; speedup vs baseline: 1.0094x; 1.0000x over previous
//
#include <hip/hip_runtime.h>
#include <stdint.h>

#define B_ 2
#define S_ 2048
#define D_ 1024
#define H_ 16
#define HD_ 64
#define D3_ 3072
#define KD_ 1024

typedef __attribute__((ext_vector_type(8))) __bf16 bf16x8;
typedef __attribute__((ext_vector_type(4))) float f32x4;
typedef __attribute__((ext_vector_type(16))) float f32x16;
typedef __attribute__((ext_vector_type(4))) unsigned int u32x4;

typedef const __attribute__((address_space(1))) unsigned int gu32_t;
typedef __attribute__((address_space(3))) unsigned int lu32_t;

static __device__ __forceinline__ unsigned short f2bf(float f) {
  unsigned int u = __float_as_uint(f);
  u += 0x7fffu + ((u >> 16) & 1u);   // RNE (inputs finite)
  return (unsigned short)(u >> 16);
}

static __device__ __forceinline__ void gll16(const unsigned short* g, unsigned short* l) {
  __builtin_amdgcn_global_load_lds((gu32_t*)(const void*)g, (lu32_t*)(void*)l, 16, 0, 0);
}

static __device__ __forceinline__ bf16x8 lds_read8(const unsigned short* p) {
  return *reinterpret_cast<const bf16x8*>(p);
}

static __device__ __forceinline__ unsigned int cvtpk(float lo, float hi) {
  unsigned int r;
  asm("v_cvt_pk_bf16_f32 %0, %1, %2" : "=v"(r) : "v"(lo), "v"(hi));
  return r;
}

static __device__ __forceinline__ void plswap(unsigned int& a, unsigned int& b) {
  asm("v_permlane32_swap_b32 %0, %1" : "+v"(a), "+v"(b));
}

// ---------------- fused prep: tcvt W_qkv | maskbits(+detect) | [tcvt W_dense] ----------------
static __device__ __forceinline__ void transpose32(const float* __restrict__ in,
                                                   unsigned short* __restrict__ out,
                                                   int K, int N, int bx, int by, int t,
                                                   float (*tsm)[33]) {
  const int k0 = by * 32, n0 = bx * 32;
  const int tx = t & 31, ty = t >> 5;
  #pragma unroll
  for (int j = 0; j < 32; j += 8) tsm[ty + j][tx] = in[(size_t)(k0 + ty + j) * N + n0 + tx];
  __syncthreads();
  #pragma unroll
  for (int j = 0; j < 32; j += 8) out[(size_t)(n0 + ty + j) * K + k0 + tx] = f2bf(tsm[tx][ty + j]);
}

__global__ void prep_kernel(const float* __restrict__ Wq, unsigned short* __restrict__ Wqt,
                            const void* __restrict__ mask,
                            unsigned long long* __restrict__ bits,
                            const float* __restrict__ Wd, unsigned short* __restrict__ Wdt) {
  __shared__ float tsm[32][33];
  __shared__ unsigned int red2[2];
  const int bid = blockIdx.x;
  const int t = threadIdx.x;
  if (bid < 3072) {
    transpose32(Wq, Wqt, KD_, D3_, bid % 96, bid / 96, t, tsm);
  } else if (bid < 4096) {
    if (t < 2) red2[t] = 0;
    __syncthreads();
    {
      const unsigned int* mw = (const unsigned int*)mask;
      unsigned int hb = 0, fl = 0;
      for (int i = t; i < 4096; i += 256) {
        unsigned int v = mw[i];
        hb |= (v & 0xFFFFFF00u);
        fl |= (v == 0x3F800000u) ? 1u : 0u;
      }
      atomicOr(&red2[0], hb);
      atomicOr(&red2[1], fl);
    }
    __syncthreads();
    const unsigned int mode = red2[1] ? 2u : (red2[0] ? 1u : 0u);
    const int lane = t & 63;
    const int nwaves = 1024 * 4;
    const int wid = ((bid - 3072) * 256 + t) >> 6;
    const int total = (B_ * S_ * S_) / 256;
    for (int wb = wid; wb < total; wb += nwaves) {
      const size_t base = (size_t)wb * 256 + lane;
      unsigned long long m0, m1, m2, m3;
      if (mode == 0) {
        const int* p = (const int*)mask;
        m0 = __ballot(p[base] != 0);       m1 = __ballot(p[base + 64] != 0);
        m2 = __ballot(p[base + 128] != 0); m3 = __ballot(p[base + 192] != 0);
      } else if (mode == 1) {
        const unsigned char* p = (const unsigned char*)mask;
        m0 = __ballot(p[base] != 0);       m1 = __ballot(p[base + 64] != 0);
        m2 = __ballot(p[base + 128] != 0); m3 = __ballot(p[base + 192] != 0);
      } else {
        const float* p = (const float*)mask;
        m0 = __ballot(p[base] != 0.f);       m1 = __ballot(p[base + 64] != 0.f);
        m2 = __ballot(p[base + 128] != 0.f); m3 = __ballot(p[base + 192] != 0.f);
      }
      if (lane < 4) {
        unsigned long long v = (lane & 1) ? m1 : m0;
        unsigned long long w2 = (lane & 1) ? m3 : m2;
        v = (lane & 2) ? w2 : v;
        bits[(size_t)wb * 4 + lane] = v;
      }
    }
  } else {
    const int bb = bid - 4096;                // 1024 blocks: W_dense 1024x1024
    transpose32(Wd, Wdt, D_, D_, bb & 31, bb >> 5, t, tsm);
  }
}

// ---------------- W_dense transpose fallback (ws too small for fused path) ----------------
__global__ void tcvt_kernel(const float* __restrict__ in, unsigned short* __restrict__ out, int K, int N) {
  __shared__ float tsm[32][33];
  transpose32(in, out, K, N, blockIdx.x, blockIdx.y, threadIdx.x, tsm);
}

// ---------------- QKV GEMM v6 (unchanged from round 16) ----------------
#define DSA256(BUF, MH, KC) \
  _Pragma("unroll") for (int fm_ = 0; fm_ < 4; ++fm_) \
    aq[fm_] = lds_read8(&Al[BUF][(wm * 128 + (MH) * 64 + fm_ * 16 + c16) * 64 + (KC)]);
#define DSB256(BUF, KC) \
  _Pragma("unroll") for (int fn_ = 0; fn_ < 3; ++fn_) \
    bq[fn_] = lds_read8(&Bl[BUF][(wn * 48 + fn_ * 16 + c16) * 64 + (KC)]);
#define MM256(MH) \
  __builtin_amdgcn_s_setprio(1); \
  _Pragma("unroll") for (int fm_ = 0; fm_ < 4; ++fm_) \
    _Pragma("unroll") for (int fn_ = 0; fn_ < 3; ++fn_) \
      acc[MH][fm_][fn_] = __builtin_amdgcn_mfma_f32_16x16x32_bf16(aq[fm_], bq[fn_], acc[MH][fm_][fn_], 0, 0, 0); \
  __builtin_amdgcn_s_setprio(0);
#define ALOAD256(KT1) \
  _Pragma("unroll") for (int q_ = 0; q_ < 4; ++q_) { \
    const float* s_ = Ag + (size_t)(q_ * 64) * KD_ + (size_t)(KT1) * 64; \
    fA[q_][0] = *reinterpret_cast<const float4*>(s_); \
    fA[q_][1] = *reinterpret_cast<const float4*>(s_ + 4); \
  }
#define AWRT256(BUF) \
  _Pragma("unroll") for (int q_ = 0; q_ < 4; ++q_) { \
    u32x4 pk_; \
    pk_[0] = cvtpk(fA[q_][0].x, fA[q_][0].y); \
    pk_[1] = cvtpk(fA[q_][0].z, fA[q_][0].w); \
    pk_[2] = cvtpk(fA[q_][1].x, fA[q_][1].y); \
    pk_[3] = cvtpk(fA[q_][1].z, fA[q_][1].w); \
    *reinterpret_cast<u32x4*>(&Al[BUF][q_ * 4096 + t * 8]) = pk_; \
  }
#define STB256(BUF, KT1) \
  _Pragma("unroll") for (int q_ = 0; q_ < 3; ++q_) \
    gll16(Bg + (size_t)(q_ * 64) * KD_ + (size_t)(KT1) * 64, &Bl[BUF][q_ * 4096 + t * 8]);

__global__ __launch_bounds__(512, 2) void gemm256_kernel(
    const float* __restrict__ Af,           // hidden f32 [4096][1024]
    const unsigned short* __restrict__ Bt,  // Wqt bf16 [3072][1024]
    const float* __restrict__ bias,
    unsigned short* __restrict__ Qh,
    unsigned short* __restrict__ Kh,
    unsigned short* __restrict__ Vt) {
  __shared__ unsigned short Al[2][16384];   // 256 rows x 64
  __shared__ unsigned short Bl[2][12288];   // 192 rows x 64
  const int t = threadIdx.x;
  const int lane = t & 63, w = t >> 6;
  const int g = lane >> 4, c16 = lane & 15;
  const int wm = w >> 2, wn = w & 3;

  const int wg = blockIdx.x;
  const int sw = (wg & 7) * 32 + (wg >> 3);
  const int by = sw >> 4, bx = sw & 15;     // 16 M-tiles x 16 N-tiles
  const int m0 = by * 256, n0 = bx * 192;

  f32x4 acc[2][4][3];
  #pragma unroll
  for (int mh = 0; mh < 2; ++mh)
    #pragma unroll
    for (int fm = 0; fm < 4; ++fm)
      #pragma unroll
      for (int fn = 0; fn < 3; ++fn)
        #pragma unroll
        for (int r = 0; r < 4; ++r) acc[mh][fm][fn][r] = 0.f;

  const int srow = t >> 3;
  const int scb = (t & 7) ^ (srow & 7);     // pre-swizzled source col-block
  const float* Ag = Af + (size_t)(m0 + srow) * KD_ + scb * 8;
  const unsigned short* Bg = Bt + (size_t)(n0 + srow) * KD_ + scb * 8;

  const int kc0 = ((g ^ (c16 & 7)) * 8);
  const int kc1 = (((4 + g) ^ (c16 & 7)) * 8);

  bf16x8 aq[4], bq[3];
  float4 fA[4][2];

  ALOAD256(0);
  STB256(0, 0);
  AWRT256(0);
  __syncthreads();

  #pragma unroll 1
  for (int kt = 0; kt < 16; ++kt) {
    const int buf = kt & 1, nb = buf ^ 1;
    const bool st = kt < 15;
    if (st) ALOAD256(kt + 1);
    DSA256(buf, 0, kc0); DSB256(buf, kc0);
    MM256(0);
    DSA256(buf, 1, kc0);
    if (st) STB256(nb, kt + 1);
    MM256(1);
    DSA256(buf, 0, kc1); DSB256(buf, kc1);
    MM256(0);
    DSA256(buf, 1, kc1);
    if (st) AWRT256(nb);
    MM256(1);
    __syncthreads();
  }

  #pragma unroll
  for (int mh = 0; mh < 2; ++mh) {
    #pragma unroll
    for (int fn = 0; fn < 3; ++fn) {
      const int n = n0 + wn * 48 + fn * 16 + c16;
      const float bv = bias[n];
      const int sel = n >> 10;          // 0:q 1:k 2:v
      const int hh = (n & 1023) >> 6;
      const int d = n & 63;
      #pragma unroll
      for (int fm = 0; fm < 4; ++fm) {
        const int m_b = m0 + wm * 128 + mh * 64 + fm * 16 + g * 4;
        const int b = m_b >> 11;
        const int s0 = m_b & 2047;
        const int bh = b * H_ + hh;
        if (sel == 2) {
          ushort4 pk;
          pk.x = f2bf(acc[mh][fm][fn][0] + bv);
          pk.y = f2bf(acc[mh][fm][fn][1] + bv);
          pk.z = f2bf(acc[mh][fm][fn][2] + bv);
          pk.w = f2bf(acc[mh][fm][fn][3] + bv);
          *reinterpret_cast<ushort4*>(&Vt[(size_t)(bh * HD_ + d) * S_ + s0]) = pk;
        } else {
          #pragma unroll
          for (int r = 0; r < 4; ++r) {
            const float v = acc[mh][fm][fn][r] + bv;
            if (sel == 0) Qh[(size_t)(bh * S_ + s0 + r) * HD_ + d] = f2bf(v * 0.18033688011112042f);
            else          Kh[(size_t)(bh * S_ + s0 + r) * HD_ + d] = f2bf(v);
          }
        }
      }
    }
  }
}

// ---------------- dense GEMM v3: 64x128 tile, 4 waves (2Mx2N), 2 blocks/CU ----------------
// Same pipelined dbuf/1-barrier discipline; grid 512 (=2/CU) doubles waves/SIMD 1->2
// vs the old 128x128 (256 blocks = 1/CU = 1 wave/SIMD, zero latency hiding).
#define DDA(BUF, KC) \
  _Pragma("unroll") for (int i_ = 0; i_ < 2; ++i_) \
    aq[i_] = lds_read8(&Al[BUF][(wr * 32 + i_ * 16 + c16) * 64 + (KC)]);
#define DDB(BUF, KC) \
  _Pragma("unroll") for (int i_ = 0; i_ < 4; ++i_) \
    bq[i_] = lds_read8(&Bl[BUF][(wc * 64 + i_ * 16 + c16) * 64 + (KC)]);
#define DMM \
  __builtin_amdgcn_s_setprio(1); \
  _Pragma("unroll") for (int mi_ = 0; mi_ < 2; ++mi_) \
    _Pragma("unroll") for (int ni_ = 0; ni_ < 4; ++ni_) \
      acc[mi_][ni_] = __builtin_amdgcn_mfma_f32_16x16x32_bf16(aq[mi_], bq[ni_], acc[mi_][ni_], 0, 0, 0); \
  __builtin_amdgcn_s_setprio(0);
#define DSTA(BUF, KT1) \
  _Pragma("unroll") for (int q_ = 0; q_ < 2; ++q_) \
    gll16(Ag + (size_t)(q_ * 32) * KD_ + (size_t)(KT1) * 64, &Al[BUF][q_ * 2048 + t * 8]);
#define DSTB(BUF, KT1) \
  _Pragma("unroll") for (int q_ = 0; q_ < 4; ++q_) \
    gll16(Bg + (size_t)(q_ * 32) * KD_ + (size_t)(KT1) * 64, &Bl[BUF][q_ * 2048 + t * 8]);

__global__ __launch_bounds__(256, 2) void gemm128p_kernel(
    const unsigned short* __restrict__ A,
    const unsigned short* __restrict__ Bt,
    const float* __restrict__ bias,
    int Ndim,
    float* __restrict__ Out) {
  __shared__ unsigned short Al[2][4096];    // 64 rows x 64
  __shared__ unsigned short Bl[2][8192];    // 128 rows x 64
  const int t = threadIdx.x;
  const int lane = t & 63, w = t >> 6;
  const int g = lane >> 4, c16 = lane & 15;
  const int wr = w >> 1, wc = w & 1;

  // bijective XCD swizzle: 512 blocks = 8 XCDs x 64
  const int wg = blockIdx.x;
  const int sw = (wg & 7) * 64 + (wg >> 3);
  const int by = sw >> 3, bx = sw & 7;      // 64 M-tiles x 8 N-tiles
  const int m0 = by * 64, n0 = bx * 128;

  f32x4 acc[2][4];
  #pragma unroll
  for (int mi = 0; mi < 2; ++mi)
    #pragma unroll
    for (int ni = 0; ni < 4; ++ni)
      #pragma unroll
      for (int r = 0; r < 4; ++r) acc[mi][ni][r] = 0.f;

  const int srow = t >> 3;
  const int scb = (t & 7) ^ (srow & 7);
  const unsigned short* Ag = A + (size_t)(m0 + srow) * KD_ + scb * 8;
  const unsigned short* Bg = Bt + (size_t)(n0 + srow) * KD_ + scb * 8;

  const int kc0 = ((g ^ (c16 & 7)) * 8);
  const int kc1 = (((4 + g) ^ (c16 & 7)) * 8);

  bf16x8 aq[2], bq[4];

  DSTA(0, 0); DSTB(0, 0);
  __syncthreads();

  #pragma unroll 1
  for (int kt = 0; kt < 16; ++kt) {
    const int buf = kt & 1, nb = buf ^ 1;
    const bool st = kt < 15;
    DDA(buf, kc0); DDB(buf, kc0);
    if (st) DSTA(nb, kt + 1);
    DMM;
    DDA(buf, kc1); DDB(buf, kc1);
    if (st) DSTB(nb, kt + 1);
    DMM;
    __syncthreads();
  }

  #pragma unroll
  for (int ni = 0; ni < 4; ++ni) {
    const int n = n0 + wc * 64 + ni * 16 + c16;
    const float bv = bias[n];
    #pragma unroll
    for (int mi = 0; mi < 2; ++mi) {
      #pragma unroll
      for (int r = 0; r < 4; ++r) {
        const int m = m0 + wr * 32 + mi * 16 + g * 4 + r;
        Out[(size_t)m * Ndim + n] = acc[mi][ni][r] + bv;
      }
    }
  }
}

// ---------------- flash attention v6 + XCD-aware block swizzle (unchanged) ----------------
#define PPOS(r) ((((r) & 3)) + 8 * ((r) >> 2))

#define SOFTPACK(SV, WQ, FLO, FHI) do {                                         \
    float p_[16];                                                               \
    _Pragma("unroll") for (int r_ = 0; r_ < 16; ++r_) {                         \
      float e_ = __builtin_amdgcn_exp2f((SV)[r_]);                              \
      int m_;                                                                   \
      asm("v_bfe_i32 %0, %1, %2, 1" : "=v"(m_) : "v"(WQ), "i"(PPOS(r_)));       \
      p_[r_] = __uint_as_float(__float_as_uint(e_) & (unsigned int)m_);         \
    }                                                                           \
    {                                                                           \
      unsigned int a0 = cvtpk(p_[0], p_[1]),  a1 = cvtpk(p_[2], p_[3]);         \
      unsigned int b0 = cvtpk(p_[4], p_[5]),  b1 = cvtpk(p_[6], p_[7]);         \
      plswap(a0, b0); plswap(a1, b1);                                           \
      u32x4 t_; t_[0] = a0; t_[1] = a1; t_[2] = b0; t_[3] = b1;                 \
      FLO = __builtin_bit_cast(bf16x8, t_);                                     \
    }                                                                           \
    {                                                                           \
      unsigned int a0 = cvtpk(p_[8], p_[9]),   a1 = cvtpk(p_[10], p_[11]);      \
      unsigned int b0 = cvtpk(p_[12], p_[13]), b1 = cvtpk(p_[14], p_[15]);      \
      plswap(a0, b0); plswap(a1, b1);                                           \
      u32x4 t_; t_[0] = a0; t_[1] = a1; t_[2] = b0; t_[3] = b1;                 \
      FHI = __builtin_bit_cast(bf16x8, t_);                                     \
    }                                                                           \
  } while (0)

#define PROC_KT(BUF, KT, WQW) do {                                              \
    f32x16 s0_;                                                                 \
    {                                                                           \
      bf16x8 kf_ = lds_read8(&sm[vp[0] + (BUF) * 8192 + (KT) * 2048]);          \
      s0_ = __builtin_amdgcn_mfma_f32_32x32x16_bf16(kf_, qf[0], zacc, 0, 0, 0); \
    }                                                                           \
    _Pragma("unroll") for (int kc_ = 1; kc_ < 4; ++kc_) {                       \
      bf16x8 kf_ = lds_read8(&sm[vp[kc_] + (BUF) * 8192 + (KT) * 2048]);        \
      s0_ = __builtin_amdgcn_mfma_f32_32x32x16_bf16(kf_, qf[kc_], s0_, 0, 0, 0); \
    }                                                                           \
    unsigned int wq_ = (WQW) >> sh4;                                            \
    bf16x8 paL_, paH_;                                                          \
    SOFTPACK(s0_, wq_, paL_, paH_);                                             \
    rsum = __builtin_amdgcn_mfma_f32_32x32x16_bf16(paL_, ones, rsum, 0, 0, 0);  \
    rsum = __builtin_amdgcn_mfma_f32_32x32x16_bf16(paH_, ones, rsum, 0, 0, 0);  \
    {                                                                           \
      bf16x8 vf0_ = lds_read8(&sm[vp[(KT)*2 + 0] + (BUF) * 8192 + 4096]);       \
      bf16x8 vf1_ = lds_read8(&sm[vp[(KT)*2 + 0] + (BUF) * 8192 + 4096 + 2048]); \
      ctx0 = __builtin_amdgcn_mfma_f32_32x32x16_bf16(paL_, vf0_, ctx0, 0, 0, 0); \
      ctx1 = __builtin_amdgcn_mfma_f32_32x32x16_bf16(paL_, vf1_, ctx1, 0, 0, 0); \
    }                                                                           \
    {                                                                           \
      bf16x8 vf0_ = lds_read8(&sm[vp[(KT)*2 + 1] + (BUF) * 8192 + 4096]);       \
      bf16x8 vf1_ = lds_read8(&sm[vp[(KT)*2 + 1] + (BUF) * 8192 + 4096 + 2048]); \
      ctx0 = __builtin_amdgcn_mfma_f32_32x32x16_bf16(paH_, vf0_, ctx0, 0, 0, 0); \
      ctx1 = __builtin_amdgcn_mfma_f32_32x32x16_bf16(paH_, vf1_, ctx1, 0, 0, 0); \
    }                                                                           \
  } while (0)

#define STAGE_TO(DBUF) do {                                                     \
    gll16(Kg,         &sm[kvb + (DBUF) * 8192 + qc1024]);                       \
    gll16(Kg + 512,   &sm[kvb + (DBUF) * 8192 + qc1024 + 512]);                 \
    gll16(Vg,         &sm[kvb + (DBUF) * 8192 + 4096 + qc1024]);                \
    gll16(Vg + 16384, &sm[kvb + (DBUF) * 8192 + 4096 + qc1024 + 512]);          \
    Kg += 4096; Vg += 64;                                                       \
  } while (0)

#define TILE64(BUF, KB, DOSTAGE) do {                                           \
    const uint2 mw_ = *(const uint2*)(mp + 2 * (KB));                           \
    if (DOSTAGE) STAGE_TO((BUF) ^ 1);                                           \
    PROC_KT(BUF, 0, mw_.x);                                                     \
    PROC_KT(BUF, 1, mw_.y);                                                     \
    __syncthreads();                                                            \
  } while (0)

__global__ __launch_bounds__(512, 4) void flash_kernel(
    const unsigned short* __restrict__ Qh,
    const unsigned short* __restrict__ Kh,
    const unsigned short* __restrict__ Vt,
    const unsigned long long* __restrict__ mbits,
    unsigned short* __restrict__ Ctx) {
  __shared__ unsigned short sm[32768];   // [grp][buf]{ K 64x64 | V 64x64 } bf16, xor-swizzled
  const int t = threadIdx.x;
  const int lane = t & 63, w = t >> 6;
  const int hi = lane >> 5, l31 = lane & 31;
  const int grp = w >> 2, qc = w & 3;

  // XCD-aware swizzle: all 16 q-tiles of one (b,h) -> same XCD (K/V L2 locality)
  const int lin = blockIdx.x;
  const int swz = (lin & 7) * 64 + (lin >> 3);
  const int qt = swz & 15, bhid = swz >> 4;
  const int h = bhid & 15, b = bhid >> 4;

  const int bh = b * H_ + h;
  const int qrow = qt * 128 + qc * 32 + l31;
  const int sh4 = hi * 4;
  const int kvb = grp * 16384;
  const int qc1024 = qc * 1024;

  bf16x8 qf[4];
  {
    const unsigned short* Qr = Qh + (size_t)(bh * S_ + qrow) * HD_ + hi * 8;
    #pragma unroll
    for (int kc = 0; kc < 4; ++kc) qf[kc] = *reinterpret_cast<const bf16x8*>(Qr + kc * 16);
  }

  f32x16 ctx0, ctx1, rsum, zacc;
  #pragma unroll
  for (int i = 0; i < 16; ++i) { ctx0[i] = 0.f; ctx1[i] = 0.f; rsum[i] = 0.f; zacc[i] = 0.f; }
  bf16x8 ones;
  #pragma unroll
  for (int i = 0; i < 8; ++i) ones[i] = (__bf16)1.0f;

  int vp[4];
  #pragma unroll
  for (int c = 0; c < 4; ++c)
    vp[c] = grp * 16384 + l31 * 64 + (((2 * c + hi) ^ (l31 & 7)) * 8);

  const unsigned int* mp =
      (const unsigned int*)(mbits + (size_t)(b * S_ + qrow) * 32) + grp * 32;

  const int srw = lane >> 3;
  const int scb = (lane & 7) ^ (srw & 7);
  const unsigned short* Kg = Kh + (size_t)(bh * S_ + grp * 1024 + qc * 16 + srw) * HD_ + scb * 8;
  const unsigned short* Vg = Vt + (size_t)(bh * HD_ + qc * 16 + srw) * S_ + grp * 1024 + scb * 8;

  STAGE_TO(0);
  __syncthreads();

  #pragma unroll 1
  for (int kb = 0; kb < 16; kb += 2) {
    TILE64(0, kb, 1);
    TILE64(1, kb + 1, (kb < 14));
  }

  // ---- combine across key-split groups (partner wave = w^4) via LDS ----
  float* creg = (float*)sm;
  if (grp == 1) {
    float* ex = creg + qc * 3072 + lane;
    #pragma unroll
    for (int r = 0; r < 16; ++r) {
      ex[r * 64] = ctx0[r];
      ex[(16 + r) * 64] = ctx1[r];
      ex[(32 + r) * 64] = rsum[r];
    }
  }
  __syncthreads();
  if (grp == 0) {
    const float* im = creg + qc * 3072 + lane;
    #pragma unroll
    for (int r = 0; r < 16; ++r) {
      const float c0 = ctx0[r] + im[r * 64];
      const float c1 = ctx1[r] + im[(16 + r) * 64];
      const float rt = rsum[r] + im[(32 + r) * 64];
      const float iv = 1.0f / rt;
      const int sq = qt * 128 + qc * 32 + PPOS(r) + 4 * hi;
      unsigned short* op = Ctx + (size_t)(b * S_ + sq) * D_ + h * HD_ + l31;
      op[0]  = f2bf(c0 * iv);
      op[32] = f2bf(c1 * iv);
    }
  }
}

extern "C" void kernel_launch(void* const* d_in, const int* in_sizes, int n_in,
                              void* d_out, int out_size, void* d_ws, size_t ws_size,
                              hipStream_t stream) {
  const float* hidden  = (const float*)d_in[0];
  const void*  mask    = d_in[1];
  const float* W_qkv   = (const float*)d_in[2];
  const float* b_qkv   = (const float*)d_in[3];
  const float* W_dense = (const float*)d_in[4];
  const float* b_dense = (const float*)d_in[5];
  float* out = (float*)d_out;

  char* ws = (char*)d_ws;
  unsigned short* Qh   = (unsigned short*)(ws);                 // 8 MB
  unsigned short* Kh   = (unsigned short*)(ws + 8388608);       // 8 MB
  unsigned short* Vtb  = (unsigned short*)(ws + 16777216);      // 8 MB
  unsigned short* Ctx  = (unsigned short*)(ws + 25165824);      // 8 MB (flash out)
  unsigned short* Wqt  = (unsigned short*)(ws + 33554432);      // 6 MB (reused for Wdt in fallback)
  unsigned long long* mbits = (unsigned long long*)(ws + 39845888); // 1 MB

  const bool fused = ws_size >= 44040192ull;
  unsigned short* Wdt = fused ? (unsigned short*)(ws + 41943040) : Wqt;

  prep_kernel<<<fused ? 5120 : 4096, 256, 0, stream>>>(
      W_qkv, Wqt, mask, mbits, W_dense, Wdt);

  gemm256_kernel<<<256, 512, 0, stream>>>(hidden, Wqt, b_qkv, Qh, Kh, Vtb);

  if (!fused)
    tcvt_kernel<<<dim3(D_ / 32, D_ / 32), 256, 0, stream>>>(W_dense, Wdt, D_, D_);

  flash_kernel<<<512, 512, 0, stream>>>(Qh, Kh, Vtb, mbits, Ctx);

  gemm128p_kernel<<<512, 256, 0, stream>>>(Ctx, Wdt, b_dense, D_, out);
}

// Round 18
// 124.649 us; speedup vs baseline: 1.0182x; 1.0087x over previous
//
#include <hip/hip_runtime.h>
#include <stdint.h>

#define B_ 2
#define S_ 2048
#define D_ 1024
#define H_ 16
#define HD_ 64
#define D3_ 3072
#define KD_ 1024

typedef __attribute__((ext_vector_type(8))) __bf16 bf16x8;
typedef __attribute__((ext_vector_type(4))) float f32x4;
typedef __attribute__((ext_vector_type(16))) float f32x16;
typedef __attribute__((ext_vector_type(4))) unsigned int u32x4;

typedef const __attribute__((address_space(1))) unsigned int gu32_t;
typedef __attribute__((address_space(3))) unsigned int lu32_t;

static __device__ __forceinline__ unsigned short f2bf(float f) {
  unsigned int u = __float_as_uint(f);
  u += 0x7fffu + ((u >> 16) & 1u);   // RNE (inputs finite)
  return (unsigned short)(u >> 16);
}

static __device__ __forceinline__ void gll16(const unsigned short* g, unsigned short* l) {
  __builtin_amdgcn_global_load_lds((gu32_t*)(const void*)g, (lu32_t*)(void*)l, 16, 0, 0);
}

static __device__ __forceinline__ bf16x8 lds_read8(const unsigned short* p) {
  return *reinterpret_cast<const bf16x8*>(p);
}

static __device__ __forceinline__ unsigned int cvtpk(float lo, float hi) {
  unsigned int r;
  asm("v_cvt_pk_bf16_f32 %0, %1, %2" : "=v"(r) : "v"(lo), "v"(hi));
  return r;
}

static __device__ __forceinline__ void plswap(unsigned int& a, unsigned int& b) {
  asm("v_permlane32_swap_b32 %0, %1" : "+v"(a), "+v"(b));
}

// ---------------- fused prep: tcvt W_qkv | maskbits(+detect) | [tcvt W_dense] ----------------
static __device__ __forceinline__ void transpose32(const float* __restrict__ in,
                                                   unsigned short* __restrict__ out,
                                                   int K, int N, int bx, int by, int t,
                                                   float (*tsm)[33]) {
  const int k0 = by * 32, n0 = bx * 32;
  const int tx = t & 31, ty = t >> 5;
  #pragma unroll
  for (int j = 0; j < 32; j += 8) tsm[ty + j][tx] = in[(size_t)(k0 + ty + j) * N + n0 + tx];
  __syncthreads();
  #pragma unroll
  for (int j = 0; j < 32; j += 8) out[(size_t)(n0 + ty + j) * K + k0 + tx] = f2bf(tsm[tx][ty + j]);
}

__global__ void prep_kernel(const float* __restrict__ Wq, unsigned short* __restrict__ Wqt,
                            const void* __restrict__ mask,
                            unsigned long long* __restrict__ bits,
                            const float* __restrict__ Wd, unsigned short* __restrict__ Wdt) {
  __shared__ float tsm[32][33];
  __shared__ unsigned int red2[2];
  const int bid = blockIdx.x;
  const int t = threadIdx.x;
  if (bid < 3072) {
    transpose32(Wq, Wqt, KD_, D3_, bid % 96, bid / 96, t, tsm);
  } else if (bid < 4096) {
    if (t < 2) red2[t] = 0;
    __syncthreads();
    {
      const unsigned int* mw = (const unsigned int*)mask;
      unsigned int hb = 0, fl = 0;
      for (int i = t; i < 4096; i += 256) {
        unsigned int v = mw[i];
        hb |= (v & 0xFFFFFF00u);
        fl |= (v == 0x3F800000u) ? 1u : 0u;
      }
      atomicOr(&red2[0], hb);
      atomicOr(&red2[1], fl);
    }
    __syncthreads();
    const unsigned int mode = red2[1] ? 2u : (red2[0] ? 1u : 0u);
    const int lane = t & 63;
    const int nwaves = 1024 * 4;
    const int wid = ((bid - 3072) * 256 + t) >> 6;
    const int total = (B_ * S_ * S_) / 256;
    for (int wb = wid; wb < total; wb += nwaves) {
      const size_t base = (size_t)wb * 256 + lane;
      unsigned long long m0, m1, m2, m3;
      if (mode == 0) {
        const int* p = (const int*)mask;
        m0 = __ballot(p[base] != 0);       m1 = __ballot(p[base + 64] != 0);
        m2 = __ballot(p[base + 128] != 0); m3 = __ballot(p[base + 192] != 0);
      } else if (mode == 1) {
        const unsigned char* p = (const unsigned char*)mask;
        m0 = __ballot(p[base] != 0);       m1 = __ballot(p[base + 64] != 0);
        m2 = __ballot(p[base + 128] != 0); m3 = __ballot(p[base + 192] != 0);
      } else {
        const float* p = (const float*)mask;
        m0 = __ballot(p[base] != 0.f);       m1 = __ballot(p[base + 64] != 0.f);
        m2 = __ballot(p[base + 128] != 0.f); m3 = __ballot(p[base + 192] != 0.f);
      }
      if (lane < 4) {
        unsigned long long v = (lane & 1) ? m1 : m0;
        unsigned long long w2 = (lane & 1) ? m3 : m2;
        v = (lane & 2) ? w2 : v;
        bits[(size_t)wb * 4 + lane] = v;
      }
    }
  } else {
    const int bb = bid - 4096;                // 1024 blocks: W_dense 1024x1024
    transpose32(Wd, Wdt, D_, D_, bb & 31, bb >> 5, t, tsm);
  }
}

// ---------------- W_dense transpose fallback (ws too small for fused path) ----------------
__global__ void tcvt_kernel(const float* __restrict__ in, unsigned short* __restrict__ out, int K, int N) {
  __shared__ float tsm[32][33];
  transpose32(in, out, K, N, blockIdx.x, blockIdx.y, threadIdx.x, tsm);
}

// ---------------- QKV GEMM v7: 128x192 tile, 4 waves, 2 blocks/CU ----------------
// Same pipelined dbuf / 1-barrier-per-K-tile / f32-A-reg-staging discipline as v6,
// retiled so TWO independent blocks share each CU: one block's MFMA covers the
// other's barrier drain (m114 cross-block overlap -- impossible at 1 block/CU).
// LDS = (128+192)x64 bf16 x2 buf = 80 KiB = exactly 2 blocks/CU. Grid 32x16 = 512.
#define DSA256(BUF, KC) \
  _Pragma("unroll") for (int fm_ = 0; fm_ < 4; ++fm_) \
    aq[fm_] = lds_read8(&Al[BUF][(wm * 64 + fm_ * 16 + c16) * 64 + (KC)]);
#define DSB256(BUF, KC) \
  _Pragma("unroll") for (int fn_ = 0; fn_ < 6; ++fn_) \
    bq[fn_] = lds_read8(&Bl[BUF][(wn * 96 + fn_ * 16 + c16) * 64 + (KC)]);
#define MM256 \
  __builtin_amdgcn_s_setprio(1); \
  _Pragma("unroll") for (int fm_ = 0; fm_ < 4; ++fm_) \
    _Pragma("unroll") for (int fn_ = 0; fn_ < 6; ++fn_) \
      acc[fm_][fn_] = __builtin_amdgcn_mfma_f32_16x16x32_bf16(aq[fm_], bq[fn_], acc[fm_][fn_], 0, 0, 0); \
  __builtin_amdgcn_s_setprio(0);
#define ALOAD256(KT1) \
  _Pragma("unroll") for (int q_ = 0; q_ < 4; ++q_) { \
    const float* s_ = Ag + (size_t)(q_ * 32) * KD_ + (size_t)(KT1) * 64; \
    fA[q_][0] = *reinterpret_cast<const float4*>(s_); \
    fA[q_][1] = *reinterpret_cast<const float4*>(s_ + 4); \
  }
#define AWRT256(BUF) \
  _Pragma("unroll") for (int q_ = 0; q_ < 4; ++q_) { \
    u32x4 pk_; \
    pk_[0] = cvtpk(fA[q_][0].x, fA[q_][0].y); \
    pk_[1] = cvtpk(fA[q_][0].z, fA[q_][0].w); \
    pk_[2] = cvtpk(fA[q_][1].x, fA[q_][1].y); \
    pk_[3] = cvtpk(fA[q_][1].z, fA[q_][1].w); \
    *reinterpret_cast<u32x4*>(&Al[BUF][q_ * 2048 + t * 8]) = pk_; \
  }
#define STB256(BUF, KT1) \
  _Pragma("unroll") for (int q_ = 0; q_ < 6; ++q_) \
    gll16(Bg + (size_t)(q_ * 32) * KD_ + (size_t)(KT1) * 64, &Bl[BUF][q_ * 2048 + t * 8]);

__global__ __launch_bounds__(256, 2) void gemm256_kernel(
    const float* __restrict__ Af,           // hidden f32 [4096][1024]
    const unsigned short* __restrict__ Bt,  // Wqt bf16 [3072][1024]
    const float* __restrict__ bias,
    unsigned short* __restrict__ Qh,
    unsigned short* __restrict__ Kh,
    unsigned short* __restrict__ Vt) {
  __shared__ unsigned short Al[2][8192];    // 128 rows x 64
  __shared__ unsigned short Bl[2][12288];   // 192 rows x 64
  const int t = threadIdx.x;
  const int lane = t & 63, w = t >> 6;
  const int g = lane >> 4, c16 = lane & 15;
  const int wm = w >> 1, wn = w & 1;

  // bijective XCD swizzle: 512 blocks = 8 XCDs x 64
  const int wg = blockIdx.x;
  const int sw = (wg & 7) * 64 + (wg >> 3);
  const int by = sw >> 4, bx = sw & 15;     // 32 M-tiles x 16 N-tiles
  const int m0 = by * 128, n0 = bx * 192;

  f32x4 acc[4][6];
  #pragma unroll
  for (int fm = 0; fm < 4; ++fm)
    #pragma unroll
    for (int fn = 0; fn < 6; ++fn)
      #pragma unroll
      for (int r = 0; r < 4; ++r) acc[fm][fn][r] = 0.f;

  // staging: thread t -> row t>>3 of each 32-row quarter, pre-swizzled source col-block
  const int srow = t >> 3;
  const int scb = (t & 7) ^ (srow & 7);
  const float* Ag = Af + (size_t)(m0 + srow) * KD_ + scb * 8;
  const unsigned short* Bg = Bt + (size_t)(n0 + srow) * KD_ + scb * 8;

  const int kc0 = ((g ^ (c16 & 7)) * 8);
  const int kc1 = (((4 + g) ^ (c16 & 7)) * 8);

  bf16x8 aq[4], bq[6];
  float4 fA[4][2];

  ALOAD256(0);
  STB256(0, 0);
  AWRT256(0);
  __syncthreads();

  #pragma unroll 1
  for (int kt = 0; kt < 16; ++kt) {
    const int buf = kt & 1, nb = buf ^ 1;
    const bool st = kt < 15;
    if (st) ALOAD256(kt + 1);               // issue f32 loads early (full-tile cover)
    DSA256(buf, kc0); DSB256(buf, kc0);
    if (st) STB256(nb, kt + 1);
    MM256;
    DSA256(buf, kc1); DSB256(buf, kc1);
    if (st) AWRT256(nb);                    // cvt + ds_write late (after all reads of buf)
    MM256;
    __syncthreads();
  }

  #pragma unroll
  for (int fn = 0; fn < 6; ++fn) {
    const int n = n0 + wn * 96 + fn * 16 + c16;
    const float bv = bias[n];
    const int sel = n >> 10;            // 0:q 1:k 2:v
    const int hh = (n & 1023) >> 6;
    const int d = n & 63;
    #pragma unroll
    for (int fm = 0; fm < 4; ++fm) {
      const int m_b = m0 + wm * 64 + fm * 16 + g * 4;
      const int b = m_b >> 11;
      const int s0 = m_b & 2047;
      const int bh = b * H_ + hh;
      if (sel == 2) {
        ushort4 pk;
        pk.x = f2bf(acc[fm][fn][0] + bv);
        pk.y = f2bf(acc[fm][fn][1] + bv);
        pk.z = f2bf(acc[fm][fn][2] + bv);
        pk.w = f2bf(acc[fm][fn][3] + bv);
        *reinterpret_cast<ushort4*>(&Vt[(size_t)(bh * HD_ + d) * S_ + s0]) = pk;
      } else {
        #pragma unroll
        for (int r = 0; r < 4; ++r) {
          const float v = acc[fm][fn][r] + bv;
          if (sel == 0) Qh[(size_t)(bh * S_ + s0 + r) * HD_ + d] = f2bf(v * 0.18033688011112042f);
          else          Kh[(size_t)(bh * S_ + s0 + r) * HD_ + d] = f2bf(v);
        }
      }
    }
  }
}

// ---------------- dense GEMM v3 (unchanged from round 17) ----------------
#define DDA(BUF, KC) \
  _Pragma("unroll") for (int i_ = 0; i_ < 2; ++i_) \
    aq[i_] = lds_read8(&Al[BUF][(wr * 32 + i_ * 16 + c16) * 64 + (KC)]);
#define DDB(BUF, KC) \
  _Pragma("unroll") for (int i_ = 0; i_ < 4; ++i_) \
    bq[i_] = lds_read8(&Bl[BUF][(wc * 64 + i_ * 16 + c16) * 64 + (KC)]);
#define DMM \
  __builtin_amdgcn_s_setprio(1); \
  _Pragma("unroll") for (int mi_ = 0; mi_ < 2; ++mi_) \
    _Pragma("unroll") for (int ni_ = 0; ni_ < 4; ++ni_) \
      acc[mi_][ni_] = __builtin_amdgcn_mfma_f32_16x16x32_bf16(aq[mi_], bq[ni_], acc[mi_][ni_], 0, 0, 0); \
  __builtin_amdgcn_s_setprio(0);
#define DSTA(BUF, KT1) \
  _Pragma("unroll") for (int q_ = 0; q_ < 2; ++q_) \
    gll16(Ag + (size_t)(q_ * 32) * KD_ + (size_t)(KT1) * 64, &Al[BUF][q_ * 2048 + t * 8]);
#define DSTB(BUF, KT1) \
  _Pragma("unroll") for (int q_ = 0; q_ < 4; ++q_) \
    gll16(Bg + (size_t)(q_ * 32) * KD_ + (size_t)(KT1) * 64, &Bl[BUF][q_ * 2048 + t * 8]);

__global__ __launch_bounds__(256, 2) void gemm128p_kernel(
    const unsigned short* __restrict__ A,
    const unsigned short* __restrict__ Bt,
    const float* __restrict__ bias,
    int Ndim,
    float* __restrict__ Out) {
  __shared__ unsigned short Al[2][4096];    // 64 rows x 64
  __shared__ unsigned short Bl[2][8192];    // 128 rows x 64
  const int t = threadIdx.x;
  const int lane = t & 63, w = t >> 6;
  const int g = lane >> 4, c16 = lane & 15;
  const int wr = w >> 1, wc = w & 1;

  const int wg = blockIdx.x;
  const int sw = (wg & 7) * 64 + (wg >> 3);
  const int by = sw >> 3, bx = sw & 7;      // 64 M-tiles x 8 N-tiles
  const int m0 = by * 64, n0 = bx * 128;

  f32x4 acc[2][4];
  #pragma unroll
  for (int mi = 0; mi < 2; ++mi)
    #pragma unroll
    for (int ni = 0; ni < 4; ++ni)
      #pragma unroll
      for (int r = 0; r < 4; ++r) acc[mi][ni][r] = 0.f;

  const int srow = t >> 3;
  const int scb = (t & 7) ^ (srow & 7);
  const unsigned short* Ag = A + (size_t)(m0 + srow) * KD_ + scb * 8;
  const unsigned short* Bg = Bt + (size_t)(n0 + srow) * KD_ + scb * 8;

  const int kc0 = ((g ^ (c16 & 7)) * 8);
  const int kc1 = (((4 + g) ^ (c16 & 7)) * 8);

  bf16x8 aq[2], bq[4];

  DSTA(0, 0); DSTB(0, 0);
  __syncthreads();

  #pragma unroll 1
  for (int kt = 0; kt < 16; ++kt) {
    const int buf = kt & 1, nb = buf ^ 1;
    const bool st = kt < 15;
    DDA(buf, kc0); DDB(buf, kc0);
    if (st) DSTA(nb, kt + 1);
    DMM;
    DDA(buf, kc1); DDB(buf, kc1);
    if (st) DSTB(nb, kt + 1);
    DMM;
    __syncthreads();
  }

  #pragma unroll
  for (int ni = 0; ni < 4; ++ni) {
    const int n = n0 + wc * 64 + ni * 16 + c16;
    const float bv = bias[n];
    #pragma unroll
    for (int mi = 0; mi < 2; ++mi) {
      #pragma unroll
      for (int r = 0; r < 4; ++r) {
        const int m = m0 + wr * 32 + mi * 16 + g * 4 + r;
        Out[(size_t)m * Ndim + n] = acc[mi][ni][r] + bv;
      }
    }
  }
}

// ---------------- flash attention v6 + XCD-aware block swizzle (unchanged) ----------------
#define PPOS(r) ((((r) & 3)) + 8 * ((r) >> 2))

#define SOFTPACK(SV, WQ, FLO, FHI) do {                                         \
    float p_[16];                                                               \
    _Pragma("unroll") for (int r_ = 0; r_ < 16; ++r_) {                         \
      float e_ = __builtin_amdgcn_exp2f((SV)[r_]);                              \
      int m_;                                                                   \
      asm("v_bfe_i32 %0, %1, %2, 1" : "=v"(m_) : "v"(WQ), "i"(PPOS(r_)));       \
      p_[r_] = __uint_as_float(__float_as_uint(e_) & (unsigned int)m_);         \
    }                                                                           \
    {                                                                           \
      unsigned int a0 = cvtpk(p_[0], p_[1]),  a1 = cvtpk(p_[2], p_[3]);         \
      unsigned int b0 = cvtpk(p_[4], p_[5]),  b1 = cvtpk(p_[6], p_[7]);         \
      plswap(a0, b0); plswap(a1, b1);                                           \
      u32x4 t_; t_[0] = a0; t_[1] = a1; t_[2] = b0; t_[3] = b1;                 \
      FLO = __builtin_bit_cast(bf16x8, t_);                                     \
    }                                                                           \
    {                                                                           \
      unsigned int a0 = cvtpk(p_[8], p_[9]),   a1 = cvtpk(p_[10], p_[11]);      \
      unsigned int b0 = cvtpk(p_[12], p_[13]), b1 = cvtpk(p_[14], p_[15]);      \
      plswap(a0, b0); plswap(a1, b1);                                           \
      u32x4 t_; t_[0] = a0; t_[1] = a1; t_[2] = b0; t_[3] = b1;                 \
      FHI = __builtin_bit_cast(bf16x8, t_);                                     \
    }                                                                           \
  } while (0)

#define PROC_KT(BUF, KT, WQW) do {                                              \
    f32x16 s0_;                                                                 \
    {                                                                           \
      bf16x8 kf_ = lds_read8(&sm[vp[0] + (BUF) * 8192 + (KT) * 2048]);          \
      s0_ = __builtin_amdgcn_mfma_f32_32x32x16_bf16(kf_, qf[0], zacc, 0, 0, 0); \
    }                                                                           \
    _Pragma("unroll") for (int kc_ = 1; kc_ < 4; ++kc_) {                       \
      bf16x8 kf_ = lds_read8(&sm[vp[kc_] + (BUF) * 8192 + (KT) * 2048]);        \
      s0_ = __builtin_amdgcn_mfma_f32_32x32x16_bf16(kf_, qf[kc_], s0_, 0, 0, 0); \
    }                                                                           \
    unsigned int wq_ = (WQW) >> sh4;                                            \
    bf16x8 paL_, paH_;                                                          \
    SOFTPACK(s0_, wq_, paL_, paH_);                                             \
    rsum = __builtin_amdgcn_mfma_f32_32x32x16_bf16(paL_, ones, rsum, 0, 0, 0);  \
    rsum = __builtin_amdgcn_mfma_f32_32x32x16_bf16(paH_, ones, rsum, 0, 0, 0);  \
    {                                                                           \
      bf16x8 vf0_ = lds_read8(&sm[vp[(KT)*2 + 0] + (BUF) * 8192 + 4096]);       \
      bf16x8 vf1_ = lds_read8(&sm[vp[(KT)*2 + 0] + (BUF) * 8192 + 4096 + 2048]); \
      ctx0 = __builtin_amdgcn_mfma_f32_32x32x16_bf16(paL_, vf0_, ctx0, 0, 0, 0); \
      ctx1 = __builtin_amdgcn_mfma_f32_32x32x16_bf16(paL_, vf1_, ctx1, 0, 0, 0); \
    }                                                                           \
    {                                                                           \
      bf16x8 vf0_ = lds_read8(&sm[vp[(KT)*2 + 1] + (BUF) * 8192 + 4096]);       \
      bf16x8 vf1_ = lds_read8(&sm[vp[(KT)*2 + 1] + (BUF) * 8192 + 4096 + 2048]); \
      ctx0 = __builtin_amdgcn_mfma_f32_32x32x16_bf16(paH_, vf0_, ctx0, 0, 0, 0); \
      ctx1 = __builtin_amdgcn_mfma_f32_32x32x16_bf16(paH_, vf1_, ctx1, 0, 0, 0); \
    }                                                                           \
  } while (0)

#define STAGE_TO(DBUF) do {                                                     \
    gll16(Kg,         &sm[kvb + (DBUF) * 8192 + qc1024]);                       \
    gll16(Kg + 512,   &sm[kvb + (DBUF) * 8192 + qc1024 + 512]);                 \
    gll16(Vg,         &sm[kvb + (DBUF) * 8192 + 4096 + qc1024]);                \
    gll16(Vg + 16384, &sm[kvb + (DBUF) * 8192 + 4096 + qc1024 + 512]);          \
    Kg += 4096; Vg += 64;                                                       \
  } while (0)

#define TILE64(BUF, KB, DOSTAGE) do {                                           \
    const uint2 mw_ = *(const uint2*)(mp + 2 * (KB));                           \
    if (DOSTAGE) STAGE_TO((BUF) ^ 1);                                           \
    PROC_KT(BUF, 0, mw_.x);                                                     \
    PROC_KT(BUF, 1, mw_.y);                                                     \
    __syncthreads();                                                            \
  } while (0)

__global__ __launch_bounds__(512, 4) void flash_kernel(
    const unsigned short* __restrict__ Qh,
    const unsigned short* __restrict__ Kh,
    const unsigned short* __restrict__ Vt,
    const unsigned long long* __restrict__ mbits,
    unsigned short* __restrict__ Ctx) {
  __shared__ unsigned short sm[32768];   // [grp][buf]{ K 64x64 | V 64x64 } bf16, xor-swizzled
  const int t = threadIdx.x;
  const int lane = t & 63, w = t >> 6;
  const int hi = lane >> 5, l31 = lane & 31;
  const int grp = w >> 2, qc = w & 3;

  // XCD-aware swizzle: all 16 q-tiles of one (b,h) -> same XCD (K/V L2 locality)
  const int lin = blockIdx.x;
  const int swz = (lin & 7) * 64 + (lin >> 3);
  const int qt = swz & 15, bhid = swz >> 4;
  const int h = bhid & 15, b = bhid >> 4;

  const int bh = b * H_ + h;
  const int qrow = qt * 128 + qc * 32 + l31;
  const int sh4 = hi * 4;
  const int kvb = grp * 16384;
  const int qc1024 = qc * 1024;

  bf16x8 qf[4];
  {
    const unsigned short* Qr = Qh + (size_t)(bh * S_ + qrow) * HD_ + hi * 8;
    #pragma unroll
    for (int kc = 0; kc < 4; ++kc) qf[kc] = *reinterpret_cast<const bf16x8*>(Qr + kc * 16);
  }

  f32x16 ctx0, ctx1, rsum, zacc;
  #pragma unroll
  for (int i = 0; i < 16; ++i) { ctx0[i] = 0.f; ctx1[i] = 0.f; rsum[i] = 0.f; zacc[i] = 0.f; }
  bf16x8 ones;
  #pragma unroll
  for (int i = 0; i < 8; ++i) ones[i] = (__bf16)1.0f;

  int vp[4];
  #pragma unroll
  for (int c = 0; c < 4; ++c)
    vp[c] = grp * 16384 + l31 * 64 + (((2 * c + hi) ^ (l31 & 7)) * 8);

  const unsigned int* mp =
      (const unsigned int*)(mbits + (size_t)(b * S_ + qrow) * 32) + grp * 32;

  const int srw = lane >> 3;
  const int scb = (lane & 7) ^ (srw & 7);
  const unsigned short* Kg = Kh + (size_t)(bh * S_ + grp * 1024 + qc * 16 + srw) * HD_ + scb * 8;
  const unsigned short* Vg = Vt + (size_t)(bh * HD_ + qc * 16 + srw) * S_ + grp * 1024 + scb * 8;

  STAGE_TO(0);
  __syncthreads();

  #pragma unroll 1
  for (int kb = 0; kb < 16; kb += 2) {
    TILE64(0, kb, 1);
    TILE64(1, kb + 1, (kb < 14));
  }

  // ---- combine across key-split groups (partner wave = w^4) via LDS ----
  float* creg = (float*)sm;
  if (grp == 1) {
    float* ex = creg + qc * 3072 + lane;
    #pragma unroll
    for (int r = 0; r < 16; ++r) {
      ex[r * 64] = ctx0[r];
      ex[(16 + r) * 64] = ctx1[r];
      ex[(32 + r) * 64] = rsum[r];
    }
  }
  __syncthreads();
  if (grp == 0) {
    const float* im = creg + qc * 3072 + lane;
    #pragma unroll
    for (int r = 0; r < 16; ++r) {
      const float c0 = ctx0[r] + im[r * 64];
      const float c1 = ctx1[r] + im[(16 + r) * 64];
      const float rt = rsum[r] + im[(32 + r) * 64];
      const float iv = 1.0f / rt;
      const int sq = qt * 128 + qc * 32 + PPOS(r) + 4 * hi;
      unsigned short* op = Ctx + (size_t)(b * S_ + sq) * D_ + h * HD_ + l31;
      op[0]  = f2bf(c0 * iv);
      op[32] = f2bf(c1 * iv);
    }
  }
}

extern "C" void kernel_launch(void* const* d_in, const int* in_sizes, int n_in,
                              void* d_out, int out_size, void* d_ws, size_t ws_size,
                              hipStream_t stream) {
  const float* hidden  = (const float*)d_in[0];
  const void*  mask    = d_in[1];
  const float* W_qkv   = (const float*)d_in[2];
  const float* b_qkv   = (const float*)d_in[3];
  const float* W_dense = (const float*)d_in[4];
  const float* b_dense = (const float*)d_in[5];
  float* out = (float*)d_out;

  char* ws = (char*)d_ws;
  unsigned short* Qh   = (unsigned short*)(ws);                 // 8 MB
  unsigned short* Kh   = (unsigned short*)(ws + 8388608);       // 8 MB
  unsigned short* Vtb  = (unsigned short*)(ws + 16777216);      // 8 MB
  unsigned short* Ctx  = (unsigned short*)(ws + 25165824);      // 8 MB (flash out)
  unsigned short* Wqt  = (unsigned short*)(ws + 33554432);      // 6 MB (reused for Wdt in fallback)
  unsigned long long* mbits = (unsigned long long*)(ws + 39845888); // 1 MB

  const bool fused = ws_size >= 44040192ull;
  unsigned short* Wdt = fused ? (unsigned short*)(ws + 41943040) : Wqt;

  prep_kernel<<<fused ? 5120 : 4096, 256, 0, stream>>>(
      W_qkv, Wqt, mask, mbits, W_dense, Wdt);

  gemm256_kernel<<<512, 256, 0, stream>>>(hidden, Wqt, b_qkv, Qh, Kh, Vtb);

  if (!fused)
    tcvt_kernel<<<dim3(D_ / 32, D_ / 32), 256, 0, stream>>>(W_dense, Wdt, D_, D_);

  flash_kernel<<<512, 512, 0, stream>>>(Qh, Kh, Vtb, mbits, Ctx);

  gemm128p_kernel<<<512, 256, 0, stream>>>(Ctx, Wdt, b_dense, D_, out);
}

// Round 19
// 122.691 us; speedup vs baseline: 1.0345x; 1.0160x over previous
//
#include <hip/hip_runtime.h>
#include <stdint.h>

#define B_ 2
#define S_ 2048
#define D_ 1024
#define H_ 16
#define HD_ 64
#define D3_ 3072
#define KD_ 1024

typedef __attribute__((ext_vector_type(8))) __bf16 bf16x8;
typedef __attribute__((ext_vector_type(4))) float f32x4;
typedef __attribute__((ext_vector_type(16))) float f32x16;
typedef __attribute__((ext_vector_type(4))) unsigned int u32x4;

typedef const __attribute__((address_space(1))) unsigned int gu32_t;
typedef __attribute__((address_space(3))) unsigned int lu32_t;

static __device__ __forceinline__ unsigned short f2bf(float f) {
  unsigned int u = __float_as_uint(f);
  u += 0x7fffu + ((u >> 16) & 1u);   // RNE (inputs finite)
  return (unsigned short)(u >> 16);
}

static __device__ __forceinline__ void gll16(const unsigned short* g, unsigned short* l) {
  __builtin_amdgcn_global_load_lds((gu32_t*)(const void*)g, (lu32_t*)(void*)l, 16, 0, 0);
}

static __device__ __forceinline__ bf16x8 lds_read8(const unsigned short* p) {
  return *reinterpret_cast<const bf16x8*>(p);
}

static __device__ __forceinline__ unsigned int cvtpk(float lo, float hi) {
  unsigned int r;
  asm("v_cvt_pk_bf16_f32 %0, %1, %2" : "=v"(r) : "v"(lo), "v"(hi));
  return r;
}

static __device__ __forceinline__ void plswap(unsigned int& a, unsigned int& b) {
  asm("v_permlane32_swap_b32 %0, %1" : "+v"(a), "+v"(b));
}

// ---------------- fused prep: tcvt W_qkv | maskbits(+detect) | [tcvt W_dense] ----------------
static __device__ __forceinline__ void transpose32(const float* __restrict__ in,
                                                   unsigned short* __restrict__ out,
                                                   int K, int N, int bx, int by, int t,
                                                   float (*tsm)[33]) {
  const int k0 = by * 32, n0 = bx * 32;
  const int tx = t & 31, ty = t >> 5;
  #pragma unroll
  for (int j = 0; j < 32; j += 8) tsm[ty + j][tx] = in[(size_t)(k0 + ty + j) * N + n0 + tx];
  __syncthreads();
  #pragma unroll
  for (int j = 0; j < 32; j += 8) out[(size_t)(n0 + ty + j) * K + k0 + tx] = f2bf(tsm[tx][ty + j]);
}

__global__ void prep_kernel(const float* __restrict__ Wq, unsigned short* __restrict__ Wqt,
                            const void* __restrict__ mask,
                            unsigned long long* __restrict__ bits,
                            const float* __restrict__ Wd, unsigned short* __restrict__ Wdt) {
  __shared__ float tsm[32][33];
  __shared__ unsigned int red2[2];
  const int bid = blockIdx.x;
  const int t = threadIdx.x;
  if (bid < 3072) {
    transpose32(Wq, Wqt, KD_, D3_, bid % 96, bid / 96, t, tsm);
  } else if (bid < 4096) {
    if (t < 2) red2[t] = 0;
    __syncthreads();
    {
      const unsigned int* mw = (const unsigned int*)mask;
      unsigned int hb = 0, fl = 0;
      for (int i = t; i < 4096; i += 256) {
        unsigned int v = mw[i];
        hb |= (v & 0xFFFFFF00u);
        fl |= (v == 0x3F800000u) ? 1u : 0u;
      }
      atomicOr(&red2[0], hb);
      atomicOr(&red2[1], fl);
    }
    __syncthreads();
    const unsigned int mode = red2[1] ? 2u : (red2[0] ? 1u : 0u);
    const int lane = t & 63;
    const int nwaves = 1024 * 4;
    const int wid = ((bid - 3072) * 256 + t) >> 6;
    const int total = (B_ * S_ * S_) / 256;
    for (int wb = wid; wb < total; wb += nwaves) {
      const size_t base = (size_t)wb * 256 + lane;
      unsigned long long m0, m1, m2, m3;
      if (mode == 0) {
        const int* p = (const int*)mask;
        m0 = __ballot(p[base] != 0);       m1 = __ballot(p[base + 64] != 0);
        m2 = __ballot(p[base + 128] != 0); m3 = __ballot(p[base + 192] != 0);
      } else if (mode == 1) {
        const unsigned char* p = (const unsigned char*)mask;
        m0 = __ballot(p[base] != 0);       m1 = __ballot(p[base + 64] != 0);
        m2 = __ballot(p[base + 128] != 0); m3 = __ballot(p[base + 192] != 0);
      } else {
        const float* p = (const float*)mask;
        m0 = __ballot(p[base] != 0.f);       m1 = __ballot(p[base + 64] != 0.f);
        m2 = __ballot(p[base + 128] != 0.f); m3 = __ballot(p[base + 192] != 0.f);
      }
      if (lane < 4) {
        unsigned long long v = (lane & 1) ? m1 : m0;
        unsigned long long w2 = (lane & 1) ? m3 : m2;
        v = (lane & 2) ? w2 : v;
        bits[(size_t)wb * 4 + lane] = v;
      }
    }
  } else {
    const int bb = bid - 4096;                // 1024 blocks: W_dense 1024x1024
    transpose32(Wd, Wdt, D_, D_, bb & 31, bb >> 5, t, tsm);
  }
}

// ---------------- W_dense transpose fallback (ws too small for fused path) ----------------
__global__ void tcvt_kernel(const float* __restrict__ in, unsigned short* __restrict__ out, int K, int N) {
  __shared__ float tsm[32][33];
  transpose32(in, out, K, N, blockIdx.x, blockIdx.y, threadIdx.x, tsm);
}

// ---------------- QKV GEMM v7 (unchanged from round 18): 128x192, 4 waves, 2 blocks/CU ----
#define DSA256(BUF, KC) \
  _Pragma("unroll") for (int fm_ = 0; fm_ < 4; ++fm_) \
    aq[fm_] = lds_read8(&Al[BUF][(wm * 64 + fm_ * 16 + c16) * 64 + (KC)]);
#define DSB256(BUF, KC) \
  _Pragma("unroll") for (int fn_ = 0; fn_ < 6; ++fn_) \
    bq[fn_] = lds_read8(&Bl[BUF][(wn * 96 + fn_ * 16 + c16) * 64 + (KC)]);
#define MM256 \
  __builtin_amdgcn_s_setprio(1); \
  _Pragma("unroll") for (int fm_ = 0; fm_ < 4; ++fm_) \
    _Pragma("unroll") for (int fn_ = 0; fn_ < 6; ++fn_) \
      acc[fm_][fn_] = __builtin_amdgcn_mfma_f32_16x16x32_bf16(aq[fm_], bq[fn_], acc[fm_][fn_], 0, 0, 0); \
  __builtin_amdgcn_s_setprio(0);
#define ALOAD256(KT1) \
  _Pragma("unroll") for (int q_ = 0; q_ < 4; ++q_) { \
    const float* s_ = Ag + (size_t)(q_ * 32) * KD_ + (size_t)(KT1) * 64; \
    fA[q_][0] = *reinterpret_cast<const float4*>(s_); \
    fA[q_][1] = *reinterpret_cast<const float4*>(s_ + 4); \
  }
#define AWRT256(BUF) \
  _Pragma("unroll") for (int q_ = 0; q_ < 4; ++q_) { \
    u32x4 pk_; \
    pk_[0] = cvtpk(fA[q_][0].x, fA[q_][0].y); \
    pk_[1] = cvtpk(fA[q_][0].z, fA[q_][0].w); \
    pk_[2] = cvtpk(fA[q_][1].x, fA[q_][1].y); \
    pk_[3] = cvtpk(fA[q_][1].z, fA[q_][1].w); \
    *reinterpret_cast<u32x4*>(&Al[BUF][q_ * 2048 + t * 8]) = pk_; \
  }
#define STB256(BUF, KT1) \
  _Pragma("unroll") for (int q_ = 0; q_ < 6; ++q_) \
    gll16(Bg + (size_t)(q_ * 32) * KD_ + (size_t)(KT1) * 64, &Bl[BUF][q_ * 2048 + t * 8]);

__global__ __launch_bounds__(256, 2) void gemm256_kernel(
    const float* __restrict__ Af,           // hidden f32 [4096][1024]
    const unsigned short* __restrict__ Bt,  // Wqt bf16 [3072][1024]
    const float* __restrict__ bias,
    unsigned short* __restrict__ Qh,
    unsigned short* __restrict__ Kh,
    unsigned short* __restrict__ Vt) {
  __shared__ unsigned short Al[2][8192];    // 128 rows x 64
  __shared__ unsigned short Bl[2][12288];   // 192 rows x 64
  const int t = threadIdx.x;
  const int lane = t & 63, w = t >> 6;
  const int g = lane >> 4, c16 = lane & 15;
  const int wm = w >> 1, wn = w & 1;

  // bijective XCD swizzle: 512 blocks = 8 XCDs x 64
  const int wg = blockIdx.x;
  const int sw = (wg & 7) * 64 + (wg >> 3);
  const int by = sw >> 4, bx = sw & 15;     // 32 M-tiles x 16 N-tiles
  const int m0 = by * 128, n0 = bx * 192;

  f32x4 acc[4][6];
  #pragma unroll
  for (int fm = 0; fm < 4; ++fm)
    #pragma unroll
    for (int fn = 0; fn < 6; ++fn)
      #pragma unroll
      for (int r = 0; r < 4; ++r) acc[fm][fn][r] = 0.f;

  const int srow = t >> 3;
  const int scb = (t & 7) ^ (srow & 7);
  const float* Ag = Af + (size_t)(m0 + srow) * KD_ + scb * 8;
  const unsigned short* Bg = Bt + (size_t)(n0 + srow) * KD_ + scb * 8;

  const int kc0 = ((g ^ (c16 & 7)) * 8);
  const int kc1 = (((4 + g) ^ (c16 & 7)) * 8);

  bf16x8 aq[4], bq[6];
  float4 fA[4][2];

  ALOAD256(0);
  STB256(0, 0);
  AWRT256(0);
  __syncthreads();

  #pragma unroll 1
  for (int kt = 0; kt < 16; ++kt) {
    const int buf = kt & 1, nb = buf ^ 1;
    const bool st = kt < 15;
    if (st) ALOAD256(kt + 1);
    DSA256(buf, kc0); DSB256(buf, kc0);
    if (st) STB256(nb, kt + 1);
    MM256;
    DSA256(buf, kc1); DSB256(buf, kc1);
    if (st) AWRT256(nb);
    MM256;
    __syncthreads();
  }

  #pragma unroll
  for (int fn = 0; fn < 6; ++fn) {
    const int n = n0 + wn * 96 + fn * 16 + c16;
    const float bv = bias[n];
    const int sel = n >> 10;            // 0:q 1:k 2:v
    const int hh = (n & 1023) >> 6;
    const int d = n & 63;
    #pragma unroll
    for (int fm = 0; fm < 4; ++fm) {
      const int m_b = m0 + wm * 64 + fm * 16 + g * 4;
      const int b = m_b >> 11;
      const int s0 = m_b & 2047;
      const int bh = b * H_ + hh;
      if (sel == 2) {
        ushort4 pk;
        pk.x = f2bf(acc[fm][fn][0] + bv);
        pk.y = f2bf(acc[fm][fn][1] + bv);
        pk.z = f2bf(acc[fm][fn][2] + bv);
        pk.w = f2bf(acc[fm][fn][3] + bv);
        *reinterpret_cast<ushort4*>(&Vt[(size_t)(bh * HD_ + d) * S_ + s0]) = pk;
      } else {
        #pragma unroll
        for (int r = 0; r < 4; ++r) {
          const float v = acc[fm][fn][r] + bv;
          if (sel == 0) Qh[(size_t)(bh * S_ + s0 + r) * HD_ + d] = f2bf(v * 0.18033688011112042f);
          else          Kh[(size_t)(bh * S_ + s0 + r) * HD_ + d] = f2bf(v);
        }
      }
    }
  }
}

// ---------------- dense GEMM v3 (unchanged from round 17) ----------------
#define DDA(BUF, KC) \
  _Pragma("unroll") for (int i_ = 0; i_ < 2; ++i_) \
    aq[i_] = lds_read8(&Al[BUF][(wr * 32 + i_ * 16 + c16) * 64 + (KC)]);
#define DDB(BUF, KC) \
  _Pragma("unroll") for (int i_ = 0; i_ < 4; ++i_) \
    bq[i_] = lds_read8(&Bl[BUF][(wc * 64 + i_ * 16 + c16) * 64 + (KC)]);
#define DMM \
  __builtin_amdgcn_s_setprio(1); \
  _Pragma("unroll") for (int mi_ = 0; mi_ < 2; ++mi_) \
    _Pragma("unroll") for (int ni_ = 0; ni_ < 4; ++ni_) \
      acc[mi_][ni_] = __builtin_amdgcn_mfma_f32_16x16x32_bf16(aq[mi_], bq[ni_], acc[mi_][ni_], 0, 0, 0); \
  __builtin_amdgcn_s_setprio(0);
#define DSTA(BUF, KT1) \
  _Pragma("unroll") for (int q_ = 0; q_ < 2; ++q_) \
    gll16(Ag + (size_t)(q_ * 32) * KD_ + (size_t)(KT1) * 64, &Al[BUF][q_ * 2048 + t * 8]);
#define DSTB(BUF, KT1) \
  _Pragma("unroll") for (int q_ = 0; q_ < 4; ++q_) \
    gll16(Bg + (size_t)(q_ * 32) * KD_ + (size_t)(KT1) * 64, &Bl[BUF][q_ * 2048 + t * 8]);

__global__ __launch_bounds__(256, 2) void gemm128p_kernel(
    const unsigned short* __restrict__ A,
    const unsigned short* __restrict__ Bt,
    const float* __restrict__ bias,
    int Ndim,
    float* __restrict__ Out) {
  __shared__ unsigned short Al[2][4096];    // 64 rows x 64
  __shared__ unsigned short Bl[2][8192];    // 128 rows x 64
  const int t = threadIdx.x;
  const int lane = t & 63, w = t >> 6;
  const int g = lane >> 4, c16 = lane & 15;
  const int wr = w >> 1, wc = w & 1;

  const int wg = blockIdx.x;
  const int sw = (wg & 7) * 64 + (wg >> 3);
  const int by = sw >> 3, bx = sw & 7;      // 64 M-tiles x 8 N-tiles
  const int m0 = by * 64, n0 = bx * 128;

  f32x4 acc[2][4];
  #pragma unroll
  for (int mi = 0; mi < 2; ++mi)
    #pragma unroll
    for (int ni = 0; ni < 4; ++ni)
      #pragma unroll
      for (int r = 0; r < 4; ++r) acc[mi][ni][r] = 0.f;

  const int srow = t >> 3;
  const int scb = (t & 7) ^ (srow & 7);
  const unsigned short* Ag = A + (size_t)(m0 + srow) * KD_ + scb * 8;
  const unsigned short* Bg = Bt + (size_t)(n0 + srow) * KD_ + scb * 8;

  const int kc0 = ((g ^ (c16 & 7)) * 8);
  const int kc1 = (((4 + g) ^ (c16 & 7)) * 8);

  bf16x8 aq[2], bq[4];

  DSTA(0, 0); DSTB(0, 0);
  __syncthreads();

  #pragma unroll 1
  for (int kt = 0; kt < 16; ++kt) {
    const int buf = kt & 1, nb = buf ^ 1;
    const bool st = kt < 15;
    DDA(buf, kc0); DDB(buf, kc0);
    if (st) DSTA(nb, kt + 1);
    DMM;
    DDA(buf, kc1); DDB(buf, kc1);
    if (st) DSTB(nb, kt + 1);
    DMM;
    __syncthreads();
  }

  #pragma unroll
  for (int ni = 0; ni < 4; ++ni) {
    const int n = n0 + wc * 64 + ni * 16 + c16;
    const float bv = bias[n];
    #pragma unroll
    for (int mi = 0; mi < 2; ++mi) {
      #pragma unroll
      for (int r = 0; r < 4; ++r) {
        const int m = m0 + wr * 32 + mi * 16 + g * 4 + r;
        Out[(size_t)m * Ndim + n] = acc[mi][ni][r] + bv;
      }
    }
  }
}

// ---------------- flash attention v7: v6 + T5 setprio around MFMA clusters ----------------
// 2 independent blocks/CU give the scheduler cross-block phase diversity; setprio(1)
// lets a block entering QK/PV issue its MFMAs ahead of the other block's SOFTPACK VALU.
#define PPOS(r) ((((r) & 3)) + 8 * ((r) >> 2))

#define SOFTPACK(SV, WQ, FLO, FHI) do {                                         \
    float p_[16];                                                               \
    _Pragma("unroll") for (int r_ = 0; r_ < 16; ++r_) {                         \
      float e_ = __builtin_amdgcn_exp2f((SV)[r_]);                              \
      int m_;                                                                   \
      asm("v_bfe_i32 %0, %1, %2, 1" : "=v"(m_) : "v"(WQ), "i"(PPOS(r_)));       \
      p_[r_] = __uint_as_float(__float_as_uint(e_) & (unsigned int)m_);         \
    }                                                                           \
    {                                                                           \
      unsigned int a0 = cvtpk(p_[0], p_[1]),  a1 = cvtpk(p_[2], p_[3]);         \
      unsigned int b0 = cvtpk(p_[4], p_[5]),  b1 = cvtpk(p_[6], p_[7]);         \
      plswap(a0, b0); plswap(a1, b1);                                           \
      u32x4 t_; t_[0] = a0; t_[1] = a1; t_[2] = b0; t_[3] = b1;                 \
      FLO = __builtin_bit_cast(bf16x8, t_);                                     \
    }                                                                           \
    {                                                                           \
      unsigned int a0 = cvtpk(p_[8], p_[9]),   a1 = cvtpk(p_[10], p_[11]);      \
      unsigned int b0 = cvtpk(p_[12], p_[13]), b1 = cvtpk(p_[14], p_[15]);      \
      plswap(a0, b0); plswap(a1, b1);                                           \
      u32x4 t_; t_[0] = a0; t_[1] = a1; t_[2] = b0; t_[3] = b1;                 \
      FHI = __builtin_bit_cast(bf16x8, t_);                                     \
    }                                                                           \
  } while (0)

#define PROC_KT(BUF, KT, WQW) do {                                              \
    f32x16 s0_;                                                                 \
    __builtin_amdgcn_s_setprio(1);                                              \
    {                                                                           \
      bf16x8 kf_ = lds_read8(&sm[vp[0] + (BUF) * 8192 + (KT) * 2048]);          \
      s0_ = __builtin_amdgcn_mfma_f32_32x32x16_bf16(kf_, qf[0], zacc, 0, 0, 0); \
    }                                                                           \
    _Pragma("unroll") for (int kc_ = 1; kc_ < 4; ++kc_) {                       \
      bf16x8 kf_ = lds_read8(&sm[vp[kc_] + (BUF) * 8192 + (KT) * 2048]);        \
      s0_ = __builtin_amdgcn_mfma_f32_32x32x16_bf16(kf_, qf[kc_], s0_, 0, 0, 0); \
    }                                                                           \
    __builtin_amdgcn_s_setprio(0);                                              \
    unsigned int wq_ = (WQW) >> sh4;                                            \
    bf16x8 paL_, paH_;                                                          \
    SOFTPACK(s0_, wq_, paL_, paH_);                                             \
    __builtin_amdgcn_s_setprio(1);                                              \
    rsum = __builtin_amdgcn_mfma_f32_32x32x16_bf16(paL_, ones, rsum, 0, 0, 0);  \
    rsum = __builtin_amdgcn_mfma_f32_32x32x16_bf16(paH_, ones, rsum, 0, 0, 0);  \
    {                                                                           \
      bf16x8 vf0_ = lds_read8(&sm[vp[(KT)*2 + 0] + (BUF) * 8192 + 4096]);       \
      bf16x8 vf1_ = lds_read8(&sm[vp[(KT)*2 + 0] + (BUF) * 8192 + 4096 + 2048]); \
      ctx0 = __builtin_amdgcn_mfma_f32_32x32x16_bf16(paL_, vf0_, ctx0, 0, 0, 0); \
      ctx1 = __builtin_amdgcn_mfma_f32_32x32x16_bf16(paL_, vf1_, ctx1, 0, 0, 0); \
    }                                                                           \
    {                                                                           \
      bf16x8 vf0_ = lds_read8(&sm[vp[(KT)*2 + 1] + (BUF) * 8192 + 4096]);       \
      bf16x8 vf1_ = lds_read8(&sm[vp[(KT)*2 + 1] + (BUF) * 8192 + 4096 + 2048]); \
      ctx0 = __builtin_amdgcn_mfma_f32_32x32x16_bf16(paH_, vf0_, ctx0, 0, 0, 0); \
      ctx1 = __builtin_amdgcn_mfma_f32_32x32x16_bf16(paH_, vf1_, ctx1, 0, 0, 0); \
    }                                                                           \
    __builtin_amdgcn_s_setprio(0);                                              \
  } while (0)

#define STAGE_TO(DBUF) do {                                                     \
    gll16(Kg,         &sm[kvb + (DBUF) * 8192 + qc1024]);                       \
    gll16(Kg + 512,   &sm[kvb + (DBUF) * 8192 + qc1024 + 512]);                 \
    gll16(Vg,         &sm[kvb + (DBUF) * 8192 + 4096 + qc1024]);                \
    gll16(Vg + 16384, &sm[kvb + (DBUF) * 8192 + 4096 + qc1024 + 512]);          \
    Kg += 4096; Vg += 64;                                                       \
  } while (0)

#define TILE64(BUF, KB, DOSTAGE) do {                                           \
    const uint2 mw_ = *(const uint2*)(mp + 2 * (KB));                           \
    if (DOSTAGE) STAGE_TO((BUF) ^ 1);                                           \
    PROC_KT(BUF, 0, mw_.x);                                                     \
    PROC_KT(BUF, 1, mw_.y);                                                     \
    __syncthreads();                                                            \
  } while (0)

__global__ __launch_bounds__(512, 4) void flash_kernel(
    const unsigned short* __restrict__ Qh,
    const unsigned short* __restrict__ Kh,
    const unsigned short* __restrict__ Vt,
    const unsigned long long* __restrict__ mbits,
    unsigned short* __restrict__ Ctx) {
  __shared__ unsigned short sm[32768];   // [grp][buf]{ K 64x64 | V 64x64 } bf16, xor-swizzled
  const int t = threadIdx.x;
  const int lane = t & 63, w = t >> 6;
  const int hi = lane >> 5, l31 = lane & 31;
  const int grp = w >> 2, qc = w & 3;

  // XCD-aware swizzle: all 16 q-tiles of one (b,h) -> same XCD (K/V L2 locality)
  const int lin = blockIdx.x;
  const int swz = (lin & 7) * 64 + (lin >> 3);
  const int qt = swz & 15, bhid = swz >> 4;
  const int h = bhid & 15, b = bhid >> 4;

  const int bh = b * H_ + h;
  const int qrow = qt * 128 + qc * 32 + l31;
  const int sh4 = hi * 4;
  const int kvb = grp * 16384;
  const int qc1024 = qc * 1024;

  bf16x8 qf[4];
  {
    const unsigned short* Qr = Qh + (size_t)(bh * S_ + qrow) * HD_ + hi * 8;
    #pragma unroll
    for (int kc = 0; kc < 4; ++kc) qf[kc] = *reinterpret_cast<const bf16x8*>(Qr + kc * 16);
  }

  f32x16 ctx0, ctx1, rsum, zacc;
  #pragma unroll
  for (int i = 0; i < 16; ++i) { ctx0[i] = 0.f; ctx1[i] = 0.f; rsum[i] = 0.f; zacc[i] = 0.f; }
  bf16x8 ones;
  #pragma unroll
  for (int i = 0; i < 8; ++i) ones[i] = (__bf16)1.0f;

  int vp[4];
  #pragma unroll
  for (int c = 0; c < 4; ++c)
    vp[c] = grp * 16384 + l31 * 64 + (((2 * c + hi) ^ (l31 & 7)) * 8);

  const unsigned int* mp =
      (const unsigned int*)(mbits + (size_t)(b * S_ + qrow) * 32) + grp * 32;

  const int srw = lane >> 3;
  const int scb = (lane & 7) ^ (srw & 7);
  const unsigned short* Kg = Kh + (size_t)(bh * S_ + grp * 1024 + qc * 16 + srw) * HD_ + scb * 8;
  const unsigned short* Vg = Vt + (size_t)(bh * HD_ + qc * 16 + srw) * S_ + grp * 1024 + scb * 8;

  STAGE_TO(0);
  __syncthreads();

  #pragma unroll 1
  for (int kb = 0; kb < 16; kb += 2) {
    TILE64(0, kb, 1);
    TILE64(1, kb + 1, (kb < 14));
  }

  // ---- combine across key-split groups (partner wave = w^4) via LDS ----
  float* creg = (float*)sm;
  if (grp == 1) {
    float* ex = creg + qc * 3072 + lane;
    #pragma unroll
    for (int r = 0; r < 16; ++r) {
      ex[r * 64] = ctx0[r];
      ex[(16 + r) * 64] = ctx1[r];
      ex[(32 + r) * 64] = rsum[r];
    }
  }
  __syncthreads();
  if (grp == 0) {
    const float* im = creg + qc * 3072 + lane;
    #pragma unroll
    for (int r = 0; r < 16; ++r) {
      const float c0 = ctx0[r] + im[r * 64];
      const float c1 = ctx1[r] + im[(16 + r) * 64];
      const float rt = rsum[r] + im[(32 + r) * 64];
      const float iv = 1.0f / rt;
      const int sq = qt * 128 + qc * 32 + PPOS(r) + 4 * hi;
      unsigned short* op = Ctx + (size_t)(b * S_ + sq) * D_ + h * HD_ + l31;
      op[0]  = f2bf(c0 * iv);
      op[32] = f2bf(c1 * iv);
    }
  }
}

extern "C" void kernel_launch(void* const* d_in, const int* in_sizes, int n_in,
                              void* d_out, int out_size, void* d_ws, size_t ws_size,
                              hipStream_t stream) {
  const float* hidden  = (const float*)d_in[0];
  const void*  mask    = d_in[1];
  const float* W_qkv   = (const float*)d_in[2];
  const float* b_qkv   = (const float*)d_in[3];
  const float* W_dense = (const float*)d_in[4];
  const float* b_dense = (const float*)d_in[5];
  float* out = (float*)d_out;

  char* ws = (char*)d_ws;
  unsigned short* Qh   = (unsigned short*)(ws);                 // 8 MB
  unsigned short* Kh   = (unsigned short*)(ws + 8388608);       // 8 MB
  unsigned short* Vtb  = (unsigned short*)(ws + 16777216);      // 8 MB
  unsigned short* Ctx  = (unsigned short*)(ws + 25165824);      // 8 MB (flash out)
  unsigned short* Wqt  = (unsigned short*)(ws + 33554432);      // 6 MB (reused for Wdt in fallback)
  unsigned long long* mbits = (unsigned long long*)(ws + 39845888); // 1 MB

  const bool fused = ws_size >= 44040192ull;
  unsigned short* Wdt = fused ? (unsigned short*)(ws + 41943040) : Wqt;

  prep_kernel<<<fused ? 5120 : 4096, 256, 0, stream>>>(
      W_qkv, Wqt, mask, mbits, W_dense, Wdt);

  gemm256_kernel<<<512, 256, 0, stream>>>(hidden, Wqt, b_qkv, Qh, Kh, Vtb);

  if (!fused)
    tcvt_kernel<<<dim3(D_ / 32, D_ / 32), 256, 0, stream>>>(W_dense, Wdt, D_, D_);

  flash_kernel<<<512, 512, 0, stream>>>(Qh, Kh, Vtb, mbits, Ctx);

  gemm128p_kernel<<<512, 256, 0, stream>>>(Ctx, Wdt, b_dense, D_, out);
}